// Round 21
// baseline (1165.270 us; speedup 1.0000x reference)
//
#include <hip/hip_runtime.h>

#define UCNT 100000
#define ICNT 50000
#define BB   3
#define NNZE 2400000
#define NN   150000   // UCNT + ICNT

#define P1B   16                  // coarse parts per behavior
#define PR1   9375                // rows per part  (16*9375 = 150000)
#define CAP1  156000              // bucket capacity (mean 150000 + 16 sigma)
#define NBKT  (BB * P1B)          // 48 buckets
#define DEPTH 192                 // fifo depth (63 residue + ~32 mean burst; >17 sigma) + overflow guard
#define FCH   64                  // flush chunk (64 * 8B = 512B contiguous)
#define P1BLK 375                 // blocks per behavior (375 * 6400 = 2400000)
#define P1CH  6400                // edges per block (13 rounds of 512, last=256)
#define CSTR  16                  // counter stride (one 64B line each)
#define HJ    8                   // hist blocks per bucket
#define P2J   128                 // chunks per bucket in p2

#define SCAN_CHUNK 4096
#define CPB ((NN + SCAN_CHUNK - 1) / SCAN_CHUNK)

// ---------------- fused zero: cnt + gcnt ------------------------------------
__global__ __launch_bounds__(256) void k_zero2(int* __restrict__ cnt,
                                               int* __restrict__ gcnt){
  long long i = (long long)blockIdx.x * blockDim.x + threadIdx.x;
  if (i < (long long)BB * NN) cnt[i] = 0;
  long long j = i - (long long)BB * NN;
  if (j >= 0 && j < NBKT * CSTR) gcnt[j] = 0;
}

// ---------------- ego -> packed bf16 table (one copy, behavior-shared) -----
__global__ __launch_bounds__(256) void k_cvt(const float* __restrict__ ue,
                                             const float* __restrict__ ie,
                                             unsigned* __restrict__ egob){
  long long w = (long long)blockIdx.x * blockDim.x + threadIdx.x; // u32 index
  if (w >= (long long)NN * 32) return;
  long long n = w >> 5;
  int pr = (int)(w & 31);
  const float* src = (n < UCNT) ? (ue + n * 64) : (ie + (n - UCNT) * 64);
  float2 v = *(const float2*)(src + pr * 2);
  unsigned a = __float_as_uint(v.x); a += 0x7FFF + ((a >> 16) & 1);
  unsigned b = __float_as_uint(v.y); b += 0x7FFF + ((b >> 16) & 1);
  egob[w] = (a >> 16) | (b & 0xFFFF0000u);
}

// ---------------- pass 1: LDS bin, 512 edges/round (13 rounds) -------------
__global__ __launch_bounds__(256) void k_p1(const int* __restrict__ rows,
                                            const int* __restrict__ cols,
                                            const float* __restrict__ vals,
                                            int* __restrict__ gcnt,
                                            int2* __restrict__ stg){
  __shared__ int2 lbuf[P1B][DEPTH];        // 24 KB
  __shared__ int  lcnt[P1B];
  int tid = threadIdx.x, lane = tid & 63, wv = tid >> 6;
  int beh = blockIdx.x / P1BLK;
  int blk = blockIdx.x - beh * P1BLK;
  long long ebase = (long long)beh * NNZE + (long long)blk * P1CH;
  if (tid < P1B) lcnt[tid] = 0;
  __syncthreads();

  for (int r = 0; r < 13; ++r){
    int off = r * 512 + tid * 2;
    if (off < P1CH){
      long long i = ebase + off;
      int2  rr = *(const int2*)(rows + i);
      int2  cc = *(const int2*)(cols + i);
      float2 vv = *(const float2*)(vals + i);
      #pragma unroll
      for (int k = 0; k < 2; ++k){
        int row = k ? rr.y : rr.x;
        int col = k ? cc.y : cc.x;
        float val = k ? vv.y : vv.x;
        int part = row / PR1;
        int2 ent = make_int2(((row - part * PR1) << 18) | col,
                             __float_as_int(val));
        int p = atomicAdd(&lcnt[part], 1);
        if (p < DEPTH){
          lbuf[part][p] = ent;
        } else {                                   // ~never: direct global
          int gb = atomicAdd(&gcnt[(beh * P1B + part) * CSTR], 1);
          if (gb < CAP1)
            stg[(long long)(beh * P1B + part) * CAP1 + gb] = ent;
        }
      }
    }
    __syncthreads();
    for (int pp = wv; pp < P1B; pp += 4){
      int n = min(lcnt[pp], DEPTH);
      int nf = n & ~(FCH - 1);
      if (nf > 0){
        int gb = 0;
        if (lane == 0) gb = atomicAdd(&gcnt[(beh * P1B + pp) * CSTR], nf);
        gb = __shfl(gb, 0);
        long long sb = (long long)(beh * P1B + pp) * CAP1;
        for (int k = lane; k < nf; k += 64)
          if (gb + k < CAP1) stg[sb + gb + k] = lbuf[pp][k];
        int res = n - nf;
        int2 t;
        if (lane < res) t = lbuf[pp][nf + lane];
        if (lane < res) lbuf[pp][lane] = t;
        if (lane == 0) lcnt[pp] = res;
      }
    }
    __syncthreads();
  }
  for (int pp = wv; pp < P1B; pp += 4){
    int n = min(lcnt[pp], DEPTH);
    if (n > 0){
      int gb = 0;
      if (lane == 0) gb = atomicAdd(&gcnt[(beh * P1B + pp) * CSTR], n);
      gb = __shfl(gb, 0);
      long long sb = (long long)(beh * P1B + pp) * CAP1;
      if (lane < n && gb + lane < CAP1) stg[sb + gb + lane] = lbuf[pp][lane];
    }
  }
}

// ---------------- hist3: LDS-private per-bucket histogram ------------------
__global__ __launch_bounds__(256) void k_hist3(const int* __restrict__ gcnt,
                                               const int2* __restrict__ stg,
                                               int* __restrict__ cnt){
  __shared__ int h[PR1];                     // 37.5 KB
  int bucket = blockIdx.x / HJ;
  int j = blockIdx.x - bucket * HJ;
  for (int i = threadIdx.x; i < PR1; i += 256) h[i] = 0;
  __syncthreads();
  int n = min(gcnt[bucket * CSTR], CAP1);
  const int2* st = stg + (long long)bucket * CAP1;
  int chunk = (n + HJ - 1) / HJ;
  int lo = j * chunk, hi = min(n, lo + chunk);
  for (int i = lo + threadIdx.x; i < hi; i += 256)
    atomicAdd(&h[(unsigned)st[i].x >> 18], 1);
  __syncthreads();
  int beh = bucket / P1B, part = bucket - beh * P1B;
  int* c = cnt + (long long)beh * NN + part * PR1;
  for (int i = threadIdx.x; i < PR1; i += 256){
    int v = h[i];
    if (v) atomicAdd(&c[i], v);
  }
}

// ---------------- scans (cnt -> rp, tp) ------------------------------------
__global__ __launch_bounds__(1024) void k_bsum(const int* __restrict__ cnt,
                                               int* __restrict__ bsum){
  int blk = blockIdx.x;
  int b = blk / CPB, ch = blk - b * CPB;
  const int* src = cnt + (long long)b * NN;
  int base = ch * SCAN_CHUNK + threadIdx.x * 4;
  int s = 0;
  #pragma unroll
  for (int k = 0; k < 4; ++k){
    int i = base + k;
    if (i < NN) s += src[i];
  }
  __shared__ int sd[1024];
  sd[threadIdx.x] = s;
  __syncthreads();
  for (int off = 512; off > 0; off >>= 1){
    if (threadIdx.x < off) sd[threadIdx.x] += sd[threadIdx.x + off];
    __syncthreads();
  }
  if (threadIdx.x == 0) bsum[blk] = sd[0];
}

__global__ __launch_bounds__(64) void k_bscan(const int* __restrict__ bsum,
                                              int* __restrict__ boff,
                                              int* __restrict__ rp){
  int b = threadIdx.x;
  if (b >= BB) return;
  int run = 0;
  for (int c = 0; c < CPB; ++c){
    boff[b * CPB + c] = run;
    run += bsum[b * CPB + c];
  }
  rp[(long long)b * (NN + 1) + NN] = run;
}

__global__ __launch_bounds__(1024) void k_scan2(const int* __restrict__ cnt,
                                                const int* __restrict__ boff,
                                                int* __restrict__ rp,
                                                int* __restrict__ tp){
  int blk = blockIdx.x;
  int b = blk / CPB, ch = blk - b * CPB;
  const int* src = cnt + (long long)b * NN;
  int* rpo = rp + (long long)b * (NN + 1);
  int* tpo = tp + (long long)b * NN;
  int base = ch * SCAN_CHUNK + threadIdx.x * 4;
  int v[4]; int tsum = 0;
  #pragma unroll
  for (int k = 0; k < 4; ++k){
    int i = base + k;
    v[k] = (i < NN) ? src[i] : 0;
    tsum += v[k];
  }
  __shared__ int sd[1024];
  sd[threadIdx.x] = tsum;
  __syncthreads();
  for (int off = 1; off < 1024; off <<= 1){
    int t = (threadIdx.x >= off) ? sd[threadIdx.x - off] : 0;
    __syncthreads();
    sd[threadIdx.x] += t;
    __syncthreads();
  }
  int excl = boff[blk] + sd[threadIdx.x] - tsum;
  #pragma unroll
  for (int k = 0; k < 4; ++k){
    int i = base + k;
    if (i < NN){ rpo[i] = excl; tpo[i] = excl; }
    excl += v[k];
  }
}

// ---------------- pass 2: ONE bucket per XCD per launch --------------------
__global__ __launch_bounds__(256) void k_p2(const int* __restrict__ gcnt,
                                            const int2* __restrict__ stg,
                                            int* __restrict__ tp,
                                            int2* __restrict__ cpk,
                                            int L){
  int x = blockIdx.x & 7;
  int j = blockIdx.x >> 3;                   // P2J chunks per bucket
  int bucket = L * 8 + x;
  int n = min(gcnt[bucket * CSTR], CAP1);
  int beh = bucket / P1B, part = bucket - beh * P1B;
  int rowbase = part * PR1;
  const int2* st = stg + (long long)bucket * CAP1;
  int* tpb = tp + (long long)beh * NN;
  int2* dst = cpk + (long long)beh * NNZE;
  int chunk = (n + P2J - 1) / P2J;
  int lo = j * chunk, hi = min(n, lo + chunk);
  for (int i = lo + threadIdx.x; i < hi; i += 256){
    int2 e = st[i];
    int row = rowbase + (int)((unsigned)e.x >> 18);
    int col = e.x & 0x3FFFF;
    int pos = atomicAdd(&tpb[row], 1);
    dst[pos] = make_int2(col, e.y);
  }
}

// ---------------- SpMM: bf16 gather table (128B/row), fp32 accumulate ------
#define GB(NK)                                                              \
  {                                                                         \
    int   c[NK]; float v[NK]; float x[NK];                                  \
    _Pragma("unroll")                                                       \
    for (int k = 0; k < NK; ++k){                                           \
      int2 q = pk[e + k];                                                   \
      c[k] = __builtin_amdgcn_readfirstlane(q.x);                           \
      v[k] = __int_as_float(__builtin_amdgcn_readfirstlane(q.y));           \
    }                                                                       \
    _Pragma("unroll")                                                       \
    for (int k = 0; k < NK; ++k){                                           \
      unsigned w = xb[(long long)c[k] * 32 + (lane >> 1)];                  \
      x[k] = __uint_as_float((lane & 1) ? (w & 0xFFFF0000u) : (w << 16));   \
    }                                                                       \
    _Pragma("unroll")                                                       \
    for (int k = 0; k < NK; ++k){                                           \
      if (k & 1) sB = fmaf(v[k], x[k], sB);                                 \
      else       sA = fmaf(v[k], x[k], sA);                                 \
    }                                                                       \
    e += NK;                                                                \
  }

template<int MODE>
__global__ __launch_bounds__(256) void k_spmmB(const int* __restrict__ rp,
                                               const int2* __restrict__ cpk,
                                               const unsigned* __restrict__ xb,
                                               const float* __restrict__ ue,
                                               const float* __restrict__ ie,
                                               unsigned* __restrict__ dstb,
                                               float* __restrict__ acc,
                                               int b){
  int row = blockIdx.x * (blockDim.x >> 6) + (threadIdx.x >> 6);  // < NN
  int lane = threadIdx.x & 63;
  row = __builtin_amdgcn_readfirstlane(row);
  const int* rpo = rp + (long long)b * (NN + 1);
  int s0 = __builtin_amdgcn_readfirstlane(rpo[row]);
  int s1 = __builtin_amdgcn_readfirstlane(rpo[row + 1]);
  const int2* pk = cpk + (long long)b * NNZE;
  float sA = 0.f, sB = 0.f;
  int e = s0;
  while (e + 16 <= s1) GB(16)
  if (e + 8 <= s1) GB(8)
  if (e + 4 <= s1) GB(4)
  if (e + 2 <= s1) GB(2)
  if (e < s1){
    int2 q = pk[e];
    int   c0 = __builtin_amdgcn_readfirstlane(q.x);
    float v0 = __int_as_float(__builtin_amdgcn_readfirstlane(q.y));
    unsigned w = xb[(long long)c0 * 32 + (lane >> 1)];
    float x0 = __uint_as_float((lane & 1) ? (w & 0xFFFF0000u) : (w << 16));
    sA = fmaf(v0, x0, sA);
  }
  float s = sA + sB;
  long long o = ((long long)b * NN + row) * 64 + lane;
  if (MODE == 0){
    float ego = (row < UCNT) ? ue[(long long)row * 64 + lane]
                             : ie[(long long)(row - UCNT) * 64 + lane];
    acc[o] = ego + s;
  } else {
    acc[o] += s;
  }
  if (MODE != 2){
    unsigned u = __float_as_uint(s);
    u += 0x7FFF + ((u >> 16) & 1);
    unsigned hb = u >> 16;                            // bf16 RN
    unsigned ot = (unsigned)__shfl_xor((int)hb, 1);
    if (!(lane & 1))
      dstb[(long long)row * 32 + (lane >> 1)] = hb | (ot << 16);
  }
}

// ---------------- attention: score pass, float4 transposed weights ---------
// sW1t[(h*16+k)*16+c] = {W1[h][4c+0][k], .., W1[h][4c+3][k]} so the inner
// product uses ONE ds_read_b128 (broadcast, conflict-free) per 4 FMAs.
// hid[3][16] lives in registers; v streams one float4 at a time.
__device__ __forceinline__ float fast_tanh(float x){
  float xc = fminf(fmaxf(x, -15.f), 15.f);
  float t = __expf(2.f * xc);
  return (t - 1.f) / (t + 1.f);
}

__global__ __launch_bounds__(256) void k_score(const float* __restrict__ acc,
                                               const float* __restrict__ W1,
                                               const float* __restrict__ W2,
                                               float* __restrict__ scbuf){
  __shared__ float4 sW1t[BB * 16 * 16];      // 12.3 KB
  __shared__ float  sW2[BB * 16];
  for (int i = threadIdx.x; i < BB * 16 * 16 * 4; i += blockDim.x){
    int j = i & 3, c = (i >> 2) & 15, k = (i >> 6) & 15, h = i >> 10;
    ((float*)&sW1t[(h * 16 + k) * 16 + c])[j] = W1[h * 1024 + (4 * c + j) * 16 + k];
  }
  if (threadIdx.x < BB * 16) sW2[threadIdx.x] = W2[threadIdx.x];
  __syncthreads();
  int t = blockIdx.x * blockDim.x + threadIdx.x;
  if (t >= BB * NN) return;
  int b = t / NN;
  int n = t - b * NN;

  const float4* src = (const float4*)(acc + ((long long)b * NN + n) * 64);
  float hid[BB][16];
  #pragma unroll
  for (int h = 0; h < BB; ++h)
    #pragma unroll
    for (int k = 0; k < 16; ++k) hid[h][k] = 0.f;

  for (int c = 0; c < 16; ++c){
    float4 v = src[c];
    v.x *= 0.25f; v.y *= 0.25f; v.z *= 0.25f; v.w *= 0.25f;
    #pragma unroll
    for (int h = 0; h < BB; ++h){
      #pragma unroll
      for (int k = 0; k < 16; ++k){
        float4 w = sW1t[(h * 16 + k) * 16 + c];
        hid[h][k] += v.x * w.x + v.y * w.y + v.z * w.z + v.w * w.w;
      }
    }
  }
  #pragma unroll
  for (int h = 0; h < BB; ++h){
    float s = 0.f;
    #pragma unroll
    for (int k = 0; k < 16; ++k) s += fast_tanh(hid[h][k]) * sW2[h * 16 + k];
    scbuf[(long long)n * 9 + h * 3 + b] = s;
  }
}

// ---------------- attention: softmax + weighted sum (thread per (n, c4)) ---
__global__ __launch_bounds__(256) void k_att2(const float* __restrict__ acc,
                                              const float* __restrict__ scbuf,
                                              float* __restrict__ out){
  int t = blockIdx.x * blockDim.x + threadIdx.x;   // NN*16 threads
  int n = t >> 4;
  int c = t & 15;
  if (n >= NN) return;
  float sc[9];
  #pragma unroll
  for (int i = 0; i < 9; ++i) sc[i] = scbuf[(long long)n * 9 + i];

  float a[BB][BB];
  #pragma unroll
  for (int h = 0; h < BB; ++h){
    float s0 = sc[h * 3], s1 = sc[h * 3 + 1], s2 = sc[h * 3 + 2];
    float m = fmaxf(fmaxf(s0, s1), s2);
    float e0 = __expf(s0 - m), e1 = __expf(s1 - m), e2 = __expf(s2 - m);
    float inv = 1.f / (e0 + e1 + e2);
    a[h][0] = e0 * inv; a[h][1] = e1 * inv; a[h][2] = e2 * inv;
  }
  float4 x0 = ((const float4*)(acc + ((long long)0 * NN + n) * 64))[c];
  float4 x1 = ((const float4*)(acc + ((long long)1 * NN + n) * 64))[c];
  float4 x2 = ((const float4*)(acc + ((long long)2 * NN + n) * 64))[c];
  x0.x *= 0.25f; x0.y *= 0.25f; x0.z *= 0.25f; x0.w *= 0.25f;
  x1.x *= 0.25f; x1.y *= 0.25f; x1.z *= 0.25f; x1.w *= 0.25f;
  x2.x *= 0.25f; x2.y *= 0.25f; x2.z *= 0.25f; x2.w *= 0.25f;
  #pragma unroll
  for (int h = 0; h < BB; ++h){
    float4 o;
    o.x = a[h][0]*x0.x + a[h][1]*x1.x + a[h][2]*x2.x;
    o.y = a[h][0]*x0.y + a[h][1]*x1.y + a[h][2]*x2.y;
    o.z = a[h][0]*x0.z + a[h][1]*x1.z + a[h][2]*x2.z;
    o.w = a[h][0]*x0.w + a[h][1]*x1.w + a[h][2]*x2.w;
    long long dst;
    if (n < UCNT) dst = ((long long)h * UCNT + n) * 64;
    else          dst = (long long)BB * UCNT * 64 + ((long long)h * ICNT + (n - UCNT)) * 64;
    ((float4*)(out + dst))[c] = o;
  }
}

// ---------------- launch ---------------------------------------------------
extern "C" void kernel_launch(void* const* d_in, const int* in_sizes, int n_in,
                              void* d_out, int out_size, void* d_ws, size_t ws_size,
                              hipStream_t stream){
  const float* ue   = (const float*)d_in[0];
  const float* ie   = (const float*)d_in[1];
  const float* W1   = (const float*)d_in[2];
  const float* W2   = (const float*)d_in[3];
  const float* vals = (const float*)d_in[4];
  const int*   rows = (const int*)d_in[5];
  const int*   cols = (const int*)d_in[6];
  float* out = (float*)d_out;

  char* ws = (char*)d_ws;
  size_t off = 0;
  auto alloc = [&](size_t bytes){ void* p = ws + off; off += (bytes + 255) & ~(size_t)255; return p; };
  float*    acc   = (float*)alloc((size_t)BB * NN * 64 * 4);   // 115.2 MB
  int2*     cpk   = (int2*)alloc((size_t)BB * NNZE * 8);       // 57.6 MB
  int2*     stg   = (int2*)alloc((size_t)NBKT * CAP1 * 8);     // 59.9 MB
  unsigned* egob  = (unsigned*)alloc((size_t)NN * 32 * 4);     // 19.2 MB
  unsigned* layb0 = (unsigned*)alloc((size_t)NN * 32 * 4);     // 19.2 MB
  unsigned* layb1 = (unsigned*)alloc((size_t)NN * 32 * 4);     // 19.2 MB
  int*      rp    = (int*)alloc((size_t)BB * (NN + 1) * 4);
  int*      tp    = (int*)alloc((size_t)BB * NN * 4);
  int*      cnt   = (int*)alloc((size_t)BB * NN * 4);
  int*      bsum  = (int*)alloc((size_t)BB * CPB * 4);
  int*      boff  = (int*)alloc((size_t)BB * CPB * 4);
  int*      gcnt  = (int*)alloc((size_t)NBKT * CSTR * 4);
  float*    scbuf = (float*)alloc((size_t)NN * 9 * 4);         // 5.4 MB
  (void)ws_size; (void)in_sizes; (void)n_in; (void)out_size;

  // CSR build + ego bf16 table
  k_zero2<<<(BB * NN + NBKT * CSTR + 255) / 256, 256, 0, stream>>>(cnt, gcnt);
  k_cvt<<<(int)(((long long)NN * 32 + 255) / 256), 256, 0, stream>>>(ue, ie, egob);
  k_p1<<<BB * P1BLK, 256, 0, stream>>>(rows, cols, vals, gcnt, stg);
  k_hist3<<<NBKT * HJ, 256, 0, stream>>>(gcnt, stg, cnt);
  k_bsum<<<BB * CPB, 1024, 0, stream>>>(cnt, bsum);
  k_bscan<<<1, 64, 0, stream>>>(bsum, boff, rp);
  k_scan2<<<BB * CPB, 1024, 0, stream>>>(cnt, boff, rp, tp);
  for (int L = 0; L < 6; ++L)
    k_p2<<<8 * P2J, 256, 0, stream>>>(gcnt, stg, tp, cpk, L);

  // propagate: one behavior per dispatch; bf16 gather tables, fp32 acc
  for (int b = 0; b < BB; ++b){
    k_spmmB<0><<<NN / 4, 256, 0, stream>>>(rp, cpk, egob,  ue, ie, layb0, acc, b);
    k_spmmB<1><<<NN / 4, 256, 0, stream>>>(rp, cpk, layb0, ue, ie, layb1, acc, b);
    k_spmmB<2><<<NN / 4, 256, 0, stream>>>(rp, cpk, layb1, ue, ie, nullptr, acc, b);
  }
  // attention: parallel score pass + streaming combine pass
  k_score<<<(BB * NN + 255) / 256, 256, 0, stream>>>(acc, W1, W2, scbuf);
  k_att2<<<(NN * 16) / 256, 256, 0, stream>>>(acc, scbuf, out);
}

// Round 22
// 1160.310 us; speedup vs baseline: 1.0043x; 1.0043x over previous
//
#include <hip/hip_runtime.h>

#define UCNT 100000
#define ICNT 50000
#define BB   3
#define NNZE 2400000
#define NN   150000   // UCNT + ICNT

#define P1B   16                  // coarse parts per behavior
#define PR1   9375                // rows per part  (16*9375 = 150000)
#define CAP1  156000              // bucket capacity (mean 150000 + 16 sigma)
#define NBKT  (BB * P1B)          // 48 buckets
#define DEPTH 192                 // fifo depth (63 residue + ~32 mean burst; >17 sigma) + overflow guard
#define FCH   64                  // flush chunk (64 * 8B = 512B contiguous)
#define P1BLK 375                 // blocks per behavior (375 * 6400 = 2400000)
#define P1CH  6400                // edges per block (13 rounds of 512, last=256)
#define CSTR  16                  // counter stride (one 64B line each)
#define HJ    8                   // hist blocks per bucket
#define P2J   128                 // chunks per bucket in p2

#define SCAN_CHUNK 4096
#define CPB ((NN + SCAN_CHUNK - 1) / SCAN_CHUNK)

// ---------------- fused zero: cnt + gcnt ------------------------------------
__global__ __launch_bounds__(256) void k_zero2(int* __restrict__ cnt,
                                               int* __restrict__ gcnt){
  long long i = (long long)blockIdx.x * blockDim.x + threadIdx.x;
  if (i < (long long)BB * NN) cnt[i] = 0;
  long long j = i - (long long)BB * NN;
  if (j >= 0 && j < NBKT * CSTR) gcnt[j] = 0;
}

// ---------------- ego -> packed bf16 table (one copy, behavior-shared) -----
__global__ __launch_bounds__(256) void k_cvt(const float* __restrict__ ue,
                                             const float* __restrict__ ie,
                                             unsigned* __restrict__ egob){
  long long w = (long long)blockIdx.x * blockDim.x + threadIdx.x; // u32 index
  if (w >= (long long)NN * 32) return;
  long long n = w >> 5;
  int pr = (int)(w & 31);
  const float* src = (n < UCNT) ? (ue + n * 64) : (ie + (n - UCNT) * 64);
  float2 v = *(const float2*)(src + pr * 2);
  unsigned a = __float_as_uint(v.x); a += 0x7FFF + ((a >> 16) & 1);
  unsigned b = __float_as_uint(v.y); b += 0x7FFF + ((b >> 16) & 1);
  egob[w] = (a >> 16) | (b & 0xFFFF0000u);
}

// ---------------- pass 1: LDS bin, 512 edges/round (13 rounds) -------------
__global__ __launch_bounds__(256) void k_p1(const int* __restrict__ rows,
                                            const int* __restrict__ cols,
                                            const float* __restrict__ vals,
                                            int* __restrict__ gcnt,
                                            int2* __restrict__ stg){
  __shared__ int2 lbuf[P1B][DEPTH];        // 24 KB
  __shared__ int  lcnt[P1B];
  int tid = threadIdx.x, lane = tid & 63, wv = tid >> 6;
  int beh = blockIdx.x / P1BLK;
  int blk = blockIdx.x - beh * P1BLK;
  long long ebase = (long long)beh * NNZE + (long long)blk * P1CH;
  if (tid < P1B) lcnt[tid] = 0;
  __syncthreads();

  for (int r = 0; r < 13; ++r){
    int off = r * 512 + tid * 2;
    if (off < P1CH){
      long long i = ebase + off;
      int2  rr = *(const int2*)(rows + i);
      int2  cc = *(const int2*)(cols + i);
      float2 vv = *(const float2*)(vals + i);
      #pragma unroll
      for (int k = 0; k < 2; ++k){
        int row = k ? rr.y : rr.x;
        int col = k ? cc.y : cc.x;
        float val = k ? vv.y : vv.x;
        int part = row / PR1;
        int2 ent = make_int2(((row - part * PR1) << 18) | col,
                             __float_as_int(val));
        int p = atomicAdd(&lcnt[part], 1);
        if (p < DEPTH){
          lbuf[part][p] = ent;
        } else {                                   // ~never: direct global
          int gb = atomicAdd(&gcnt[(beh * P1B + part) * CSTR], 1);
          if (gb < CAP1)
            stg[(long long)(beh * P1B + part) * CAP1 + gb] = ent;
        }
      }
    }
    __syncthreads();
    for (int pp = wv; pp < P1B; pp += 4){
      int n = min(lcnt[pp], DEPTH);
      int nf = n & ~(FCH - 1);
      if (nf > 0){
        int gb = 0;
        if (lane == 0) gb = atomicAdd(&gcnt[(beh * P1B + pp) * CSTR], nf);
        gb = __shfl(gb, 0);
        long long sb = (long long)(beh * P1B + pp) * CAP1;
        for (int k = lane; k < nf; k += 64)
          if (gb + k < CAP1) stg[sb + gb + k] = lbuf[pp][k];
        int res = n - nf;
        int2 t;
        if (lane < res) t = lbuf[pp][nf + lane];
        if (lane < res) lbuf[pp][lane] = t;
        if (lane == 0) lcnt[pp] = res;
      }
    }
    __syncthreads();
  }
  for (int pp = wv; pp < P1B; pp += 4){
    int n = min(lcnt[pp], DEPTH);
    if (n > 0){
      int gb = 0;
      if (lane == 0) gb = atomicAdd(&gcnt[(beh * P1B + pp) * CSTR], n);
      gb = __shfl(gb, 0);
      long long sb = (long long)(beh * P1B + pp) * CAP1;
      if (lane < n && gb + lane < CAP1) stg[sb + gb + lane] = lbuf[pp][lane];
    }
  }
}

// ---------------- hist3: LDS-private per-bucket histogram ------------------
__global__ __launch_bounds__(256) void k_hist3(const int* __restrict__ gcnt,
                                               const int2* __restrict__ stg,
                                               int* __restrict__ cnt){
  __shared__ int h[PR1];                     // 37.5 KB
  int bucket = blockIdx.x / HJ;
  int j = blockIdx.x - bucket * HJ;
  for (int i = threadIdx.x; i < PR1; i += 256) h[i] = 0;
  __syncthreads();
  int n = min(gcnt[bucket * CSTR], CAP1);
  const int2* st = stg + (long long)bucket * CAP1;
  int chunk = (n + HJ - 1) / HJ;
  int lo = j * chunk, hi = min(n, lo + chunk);
  for (int i = lo + threadIdx.x; i < hi; i += 256)
    atomicAdd(&h[(unsigned)st[i].x >> 18], 1);
  __syncthreads();
  int beh = bucket / P1B, part = bucket - beh * P1B;
  int* c = cnt + (long long)beh * NN + part * PR1;
  for (int i = threadIdx.x; i < PR1; i += 256){
    int v = h[i];
    if (v) atomicAdd(&c[i], v);
  }
}

// ---------------- scans (cnt -> rp, tp) ------------------------------------
__global__ __launch_bounds__(1024) void k_bsum(const int* __restrict__ cnt,
                                               int* __restrict__ bsum){
  int blk = blockIdx.x;
  int b = blk / CPB, ch = blk - b * CPB;
  const int* src = cnt + (long long)b * NN;
  int base = ch * SCAN_CHUNK + threadIdx.x * 4;
  int s = 0;
  #pragma unroll
  for (int k = 0; k < 4; ++k){
    int i = base + k;
    if (i < NN) s += src[i];
  }
  __shared__ int sd[1024];
  sd[threadIdx.x] = s;
  __syncthreads();
  for (int off = 512; off > 0; off >>= 1){
    if (threadIdx.x < off) sd[threadIdx.x] += sd[threadIdx.x + off];
    __syncthreads();
  }
  if (threadIdx.x == 0) bsum[blk] = sd[0];
}

__global__ __launch_bounds__(64) void k_bscan(const int* __restrict__ bsum,
                                              int* __restrict__ boff,
                                              int* __restrict__ rp){
  int b = threadIdx.x;
  if (b >= BB) return;
  int run = 0;
  for (int c = 0; c < CPB; ++c){
    boff[b * CPB + c] = run;
    run += bsum[b * CPB + c];
  }
  rp[(long long)b * (NN + 1) + NN] = run;
}

__global__ __launch_bounds__(1024) void k_scan2(const int* __restrict__ cnt,
                                                const int* __restrict__ boff,
                                                int* __restrict__ rp,
                                                int* __restrict__ tp){
  int blk = blockIdx.x;
  int b = blk / CPB, ch = blk - b * CPB;
  const int* src = cnt + (long long)b * NN;
  int* rpo = rp + (long long)b * (NN + 1);
  int* tpo = tp + (long long)b * NN;
  int base = ch * SCAN_CHUNK + threadIdx.x * 4;
  int v[4]; int tsum = 0;
  #pragma unroll
  for (int k = 0; k < 4; ++k){
    int i = base + k;
    v[k] = (i < NN) ? src[i] : 0;
    tsum += v[k];
  }
  __shared__ int sd[1024];
  sd[threadIdx.x] = tsum;
  __syncthreads();
  for (int off = 1; off < 1024; off <<= 1){
    int t = (threadIdx.x >= off) ? sd[threadIdx.x - off] : 0;
    __syncthreads();
    sd[threadIdx.x] += t;
    __syncthreads();
  }
  int excl = boff[blk] + sd[threadIdx.x] - tsum;
  #pragma unroll
  for (int k = 0; k < 4; ++k){
    int i = base + k;
    if (i < NN){ rpo[i] = excl; tpo[i] = excl; }
    excl += v[k];
  }
}

// ---------------- pass 2: ONE bucket per XCD per launch --------------------
__global__ __launch_bounds__(256) void k_p2(const int* __restrict__ gcnt,
                                            const int2* __restrict__ stg,
                                            int* __restrict__ tp,
                                            int2* __restrict__ cpk,
                                            int L){
  int x = blockIdx.x & 7;
  int j = blockIdx.x >> 3;                   // P2J chunks per bucket
  int bucket = L * 8 + x;
  int n = min(gcnt[bucket * CSTR], CAP1);
  int beh = bucket / P1B, part = bucket - beh * P1B;
  int rowbase = part * PR1;
  const int2* st = stg + (long long)bucket * CAP1;
  int* tpb = tp + (long long)beh * NN;
  int2* dst = cpk + (long long)beh * NNZE;
  int chunk = (n + P2J - 1) / P2J;
  int lo = j * chunk, hi = min(n, lo + chunk);
  for (int i = lo + threadIdx.x; i < hi; i += 256){
    int2 e = st[i];
    int row = rowbase + (int)((unsigned)e.x >> 18);
    int col = e.x & 0x3FFFF;
    int pos = atomicAdd(&tpb[row], 1);
    dst[pos] = make_int2(col, e.y);
  }
}

// ---------------- SpMM: bf16 gather table (128B/row), fp32 accumulate ------
#define GB(NK)                                                              \
  {                                                                         \
    int   c[NK]; float v[NK]; float x[NK];                                  \
    _Pragma("unroll")                                                       \
    for (int k = 0; k < NK; ++k){                                           \
      int2 q = pk[e + k];                                                   \
      c[k] = __builtin_amdgcn_readfirstlane(q.x);                           \
      v[k] = __int_as_float(__builtin_amdgcn_readfirstlane(q.y));           \
    }                                                                       \
    _Pragma("unroll")                                                       \
    for (int k = 0; k < NK; ++k){                                           \
      unsigned w = xb[(long long)c[k] * 32 + (lane >> 1)];                  \
      x[k] = __uint_as_float((lane & 1) ? (w & 0xFFFF0000u) : (w << 16));   \
    }                                                                       \
    _Pragma("unroll")                                                       \
    for (int k = 0; k < NK; ++k){                                           \
      if (k & 1) sB = fmaf(v[k], x[k], sB);                                 \
      else       sA = fmaf(v[k], x[k], sA);                                 \
    }                                                                       \
    e += NK;                                                                \
  }

template<int MODE>
__global__ __launch_bounds__(256) void k_spmmB(const int* __restrict__ rp,
                                               const int2* __restrict__ cpk,
                                               const unsigned* __restrict__ xb,
                                               const float* __restrict__ ue,
                                               const float* __restrict__ ie,
                                               unsigned* __restrict__ dstb,
                                               float* __restrict__ acc,
                                               int b){
  int row = blockIdx.x * (blockDim.x >> 6) + (threadIdx.x >> 6);  // < NN
  int lane = threadIdx.x & 63;
  row = __builtin_amdgcn_readfirstlane(row);
  const int* rpo = rp + (long long)b * (NN + 1);
  int s0 = __builtin_amdgcn_readfirstlane(rpo[row]);
  int s1 = __builtin_amdgcn_readfirstlane(rpo[row + 1]);
  const int2* pk = cpk + (long long)b * NNZE;
  float sA = 0.f, sB = 0.f;
  int e = s0;
  while (e + 16 <= s1) GB(16)
  if (e + 8 <= s1) GB(8)
  if (e + 4 <= s1) GB(4)
  if (e + 2 <= s1) GB(2)
  if (e < s1){
    int2 q = pk[e];
    int   c0 = __builtin_amdgcn_readfirstlane(q.x);
    float v0 = __int_as_float(__builtin_amdgcn_readfirstlane(q.y));
    unsigned w = xb[(long long)c0 * 32 + (lane >> 1)];
    float x0 = __uint_as_float((lane & 1) ? (w & 0xFFFF0000u) : (w << 16));
    sA = fmaf(v0, x0, sA);
  }
  float s = sA + sB;
  long long o = ((long long)b * NN + row) * 64 + lane;
  if (MODE == 0){
    float ego = (row < UCNT) ? ue[(long long)row * 64 + lane]
                             : ie[(long long)(row - UCNT) * 64 + lane];
    acc[o] = ego + s;
  } else {
    acc[o] += s;
  }
  if (MODE != 2){
    unsigned u = __float_as_uint(s);
    u += 0x7FFF + ((u >> 16) & 1);
    unsigned hb = u >> 16;                            // bf16 RN
    unsigned ot = (unsigned)__shfl_xor((int)hb, 1);
    if (!(lane & 1))
      dstb[(long long)row * 32 + (lane >> 1)] = hb | (ot << 16);
  }
}

// ---------------- attention: score pass — burst row load + float4 weights --
// v[16] loaded in one contiguous burst (4 lines/thread, perfect utilization,
// R20's good memory pattern) + transposed float4 LDS weights and hid[3][16]
// register accumulators (R21's good compute pattern).
__device__ __forceinline__ float fast_tanh(float x){
  float xc = fminf(fmaxf(x, -15.f), 15.f);
  float t = __expf(2.f * xc);
  return (t - 1.f) / (t + 1.f);
}

__global__ __launch_bounds__(256) void k_score(const float* __restrict__ acc,
                                               const float* __restrict__ W1,
                                               const float* __restrict__ W2,
                                               float* __restrict__ scbuf){
  __shared__ float4 sW1t[BB * 16 * 16];      // 12.3 KB
  __shared__ float  sW2[BB * 16];
  for (int i = threadIdx.x; i < BB * 16 * 16 * 4; i += blockDim.x){
    int j = i & 3, c = (i >> 2) & 15, k = (i >> 6) & 15, h = i >> 10;
    ((float*)&sW1t[(h * 16 + k) * 16 + c])[j] = W1[h * 1024 + (4 * c + j) * 16 + k];
  }
  if (threadIdx.x < BB * 16) sW2[threadIdx.x] = W2[threadIdx.x];
  __syncthreads();
  int t = blockIdx.x * blockDim.x + threadIdx.x;
  if (t >= BB * NN) return;
  int b = t / NN;
  int n = t - b * NN;

  const float4* src = (const float4*)(acc + ((long long)b * NN + n) * 64);
  float4 v[16];
  #pragma unroll
  for (int c = 0; c < 16; ++c){
    v[c] = src[c];
    v[c].x *= 0.25f; v[c].y *= 0.25f; v[c].z *= 0.25f; v[c].w *= 0.25f;
  }
  float hid[BB][16];
  #pragma unroll
  for (int h = 0; h < BB; ++h)
    #pragma unroll
    for (int k = 0; k < 16; ++k) hid[h][k] = 0.f;

  #pragma unroll
  for (int c = 0; c < 16; ++c){
    #pragma unroll
    for (int h = 0; h < BB; ++h){
      #pragma unroll
      for (int k = 0; k < 16; ++k){
        float4 w = sW1t[(h * 16 + k) * 16 + c];
        hid[h][k] += v[c].x * w.x + v[c].y * w.y + v[c].z * w.z + v[c].w * w.w;
      }
    }
  }
  #pragma unroll
  for (int h = 0; h < BB; ++h){
    float s = 0.f;
    #pragma unroll
    for (int k = 0; k < 16; ++k) s += fast_tanh(hid[h][k]) * sW2[h * 16 + k];
    scbuf[(long long)n * 9 + h * 3 + b] = s;
  }
}

// ---------------- attention: softmax + weighted sum (thread per (n, c4)) ---
__global__ __launch_bounds__(256) void k_att2(const float* __restrict__ acc,
                                              const float* __restrict__ scbuf,
                                              float* __restrict__ out){
  int t = blockIdx.x * blockDim.x + threadIdx.x;   // NN*16 threads
  int n = t >> 4;
  int c = t & 15;
  if (n >= NN) return;
  float sc[9];
  #pragma unroll
  for (int i = 0; i < 9; ++i) sc[i] = scbuf[(long long)n * 9 + i];

  float a[BB][BB];
  #pragma unroll
  for (int h = 0; h < BB; ++h){
    float s0 = sc[h * 3], s1 = sc[h * 3 + 1], s2 = sc[h * 3 + 2];
    float m = fmaxf(fmaxf(s0, s1), s2);
    float e0 = __expf(s0 - m), e1 = __expf(s1 - m), e2 = __expf(s2 - m);
    float inv = 1.f / (e0 + e1 + e2);
    a[h][0] = e0 * inv; a[h][1] = e1 * inv; a[h][2] = e2 * inv;
  }
  float4 x0 = ((const float4*)(acc + ((long long)0 * NN + n) * 64))[c];
  float4 x1 = ((const float4*)(acc + ((long long)1 * NN + n) * 64))[c];
  float4 x2 = ((const float4*)(acc + ((long long)2 * NN + n) * 64))[c];
  x0.x *= 0.25f; x0.y *= 0.25f; x0.z *= 0.25f; x0.w *= 0.25f;
  x1.x *= 0.25f; x1.y *= 0.25f; x1.z *= 0.25f; x1.w *= 0.25f;
  x2.x *= 0.25f; x2.y *= 0.25f; x2.z *= 0.25f; x2.w *= 0.25f;
  #pragma unroll
  for (int h = 0; h < BB; ++h){
    float4 o;
    o.x = a[h][0]*x0.x + a[h][1]*x1.x + a[h][2]*x2.x;
    o.y = a[h][0]*x0.y + a[h][1]*x1.y + a[h][2]*x2.y;
    o.z = a[h][0]*x0.z + a[h][1]*x1.z + a[h][2]*x2.z;
    o.w = a[h][0]*x0.w + a[h][1]*x1.w + a[h][2]*x2.w;
    long long dst;
    if (n < UCNT) dst = ((long long)h * UCNT + n) * 64;
    else          dst = (long long)BB * UCNT * 64 + ((long long)h * ICNT + (n - UCNT)) * 64;
    ((float4*)(out + dst))[c] = o;
  }
}

// ---------------- launch ---------------------------------------------------
extern "C" void kernel_launch(void* const* d_in, const int* in_sizes, int n_in,
                              void* d_out, int out_size, void* d_ws, size_t ws_size,
                              hipStream_t stream){
  const float* ue   = (const float*)d_in[0];
  const float* ie   = (const float*)d_in[1];
  const float* W1   = (const float*)d_in[2];
  const float* W2   = (const float*)d_in[3];
  const float* vals = (const float*)d_in[4];
  const int*   rows = (const int*)d_in[5];
  const int*   cols = (const int*)d_in[6];
  float* out = (float*)d_out;

  char* ws = (char*)d_ws;
  size_t off = 0;
  auto alloc = [&](size_t bytes){ void* p = ws + off; off += (bytes + 255) & ~(size_t)255; return p; };
  float*    acc   = (float*)alloc((size_t)BB * NN * 64 * 4);   // 115.2 MB
  int2*     cpk   = (int2*)alloc((size_t)BB * NNZE * 8);       // 57.6 MB
  int2*     stg   = (int2*)alloc((size_t)NBKT * CAP1 * 8);     // 59.9 MB
  unsigned* egob  = (unsigned*)alloc((size_t)NN * 32 * 4);     // 19.2 MB
  unsigned* layb0 = (unsigned*)alloc((size_t)NN * 32 * 4);     // 19.2 MB
  unsigned* layb1 = (unsigned*)alloc((size_t)NN * 32 * 4);     // 19.2 MB
  int*      rp    = (int*)alloc((size_t)BB * (NN + 1) * 4);
  int*      tp    = (int*)alloc((size_t)BB * NN * 4);
  int*      cnt   = (int*)alloc((size_t)BB * NN * 4);
  int*      bsum  = (int*)alloc((size_t)BB * CPB * 4);
  int*      boff  = (int*)alloc((size_t)BB * CPB * 4);
  int*      gcnt  = (int*)alloc((size_t)NBKT * CSTR * 4);
  float*    scbuf = (float*)alloc((size_t)NN * 9 * 4);         // 5.4 MB
  (void)ws_size; (void)in_sizes; (void)n_in; (void)out_size;

  // CSR build + ego bf16 table
  k_zero2<<<(BB * NN + NBKT * CSTR + 255) / 256, 256, 0, stream>>>(cnt, gcnt);
  k_cvt<<<(int)(((long long)NN * 32 + 255) / 256), 256, 0, stream>>>(ue, ie, egob);
  k_p1<<<BB * P1BLK, 256, 0, stream>>>(rows, cols, vals, gcnt, stg);
  k_hist3<<<NBKT * HJ, 256, 0, stream>>>(gcnt, stg, cnt);
  k_bsum<<<BB * CPB, 1024, 0, stream>>>(cnt, bsum);
  k_bscan<<<1, 64, 0, stream>>>(bsum, boff, rp);
  k_scan2<<<BB * CPB, 1024, 0, stream>>>(cnt, boff, rp, tp);
  for (int L = 0; L < 6; ++L)
    k_p2<<<8 * P2J, 256, 0, stream>>>(gcnt, stg, tp, cpk, L);

  // propagate: one behavior per dispatch; bf16 gather tables, fp32 acc
  for (int b = 0; b < BB; ++b){
    k_spmmB<0><<<NN / 4, 256, 0, stream>>>(rp, cpk, egob,  ue, ie, layb0, acc, b);
    k_spmmB<1><<<NN / 4, 256, 0, stream>>>(rp, cpk, layb0, ue, ie, layb1, acc, b);
    k_spmmB<2><<<NN / 4, 256, 0, stream>>>(rp, cpk, layb1, ue, ie, nullptr, acc, b);
  }
  // attention: parallel score pass + streaming combine pass
  k_score<<<(BB * NN + 255) / 256, 256, 0, stream>>>(acc, W1, W2, scbuf);
  k_att2<<<(NN * 16) / 256, 256, 0, stream>>>(acc, scbuf, out);
}

// Round 23
// 1127.556 us; speedup vs baseline: 1.0334x; 1.0290x over previous
//
#include <hip/hip_runtime.h>

#define UCNT 100000
#define ICNT 50000
#define BB   3
#define NNZE 2400000
#define NN   150000   // UCNT + ICNT

#define P1B   16                  // coarse parts per behavior
#define PR1   9375                // rows per part  (16*9375 = 150000)
#define CAP1  156000              // bucket capacity (mean 150000 + 16 sigma)
#define NBKT  (BB * P1B)          // 48 buckets
#define DEPTH 192                 // fifo depth (63 residue + ~32 mean burst; >17 sigma) + overflow guard
#define FCH   64                  // flush chunk (64 * 8B = 512B contiguous)
#define P1BLK 375                 // blocks per behavior (375 * 6400 = 2400000)
#define P1CH  6400                // edges per block (13 rounds of 512, last=256)
#define CSTR  16                  // counter stride (one 64B line each)
#define HJ    8                   // hist blocks per bucket
#define P2J   128                 // chunks per bucket in p2

#define SCAN_CHUNK 4096
#define CPB ((NN + SCAN_CHUNK - 1) / SCAN_CHUNK)

// ---------------- fused zero: cnt + gcnt ------------------------------------
__global__ __launch_bounds__(256) void k_zero2(int* __restrict__ cnt,
                                               int* __restrict__ gcnt){
  long long i = (long long)blockIdx.x * blockDim.x + threadIdx.x;
  if (i < (long long)BB * NN) cnt[i] = 0;
  long long j = i - (long long)BB * NN;
  if (j >= 0 && j < NBKT * CSTR) gcnt[j] = 0;
}

// ---------------- ego -> packed bf16 table (one copy, behavior-shared) -----
__global__ __launch_bounds__(256) void k_cvt(const float* __restrict__ ue,
                                             const float* __restrict__ ie,
                                             unsigned* __restrict__ egob){
  long long w = (long long)blockIdx.x * blockDim.x + threadIdx.x; // u32 index
  if (w >= (long long)NN * 32) return;
  long long n = w >> 5;
  int pr = (int)(w & 31);
  const float* src = (n < UCNT) ? (ue + n * 64) : (ie + (n - UCNT) * 64);
  float2 v = *(const float2*)(src + pr * 2);
  unsigned a = __float_as_uint(v.x); a += 0x7FFF + ((a >> 16) & 1);
  unsigned b = __float_as_uint(v.y); b += 0x7FFF + ((b >> 16) & 1);
  egob[w] = (a >> 16) | (b & 0xFFFF0000u);
}

// ---------------- pass 1: LDS bin, 512 edges/round (13 rounds) -------------
__global__ __launch_bounds__(256) void k_p1(const int* __restrict__ rows,
                                            const int* __restrict__ cols,
                                            const float* __restrict__ vals,
                                            int* __restrict__ gcnt,
                                            int2* __restrict__ stg){
  __shared__ int2 lbuf[P1B][DEPTH];        // 24 KB
  __shared__ int  lcnt[P1B];
  int tid = threadIdx.x, lane = tid & 63, wv = tid >> 6;
  int beh = blockIdx.x / P1BLK;
  int blk = blockIdx.x - beh * P1BLK;
  long long ebase = (long long)beh * NNZE + (long long)blk * P1CH;
  if (tid < P1B) lcnt[tid] = 0;
  __syncthreads();

  for (int r = 0; r < 13; ++r){
    int off = r * 512 + tid * 2;
    if (off < P1CH){
      long long i = ebase + off;
      int2  rr = *(const int2*)(rows + i);
      int2  cc = *(const int2*)(cols + i);
      float2 vv = *(const float2*)(vals + i);
      #pragma unroll
      for (int k = 0; k < 2; ++k){
        int row = k ? rr.y : rr.x;
        int col = k ? cc.y : cc.x;
        float val = k ? vv.y : vv.x;
        int part = row / PR1;
        int2 ent = make_int2(((row - part * PR1) << 18) | col,
                             __float_as_int(val));
        int p = atomicAdd(&lcnt[part], 1);
        if (p < DEPTH){
          lbuf[part][p] = ent;
        } else {                                   // ~never: direct global
          int gb = atomicAdd(&gcnt[(beh * P1B + part) * CSTR], 1);
          if (gb < CAP1)
            stg[(long long)(beh * P1B + part) * CAP1 + gb] = ent;
        }
      }
    }
    __syncthreads();
    for (int pp = wv; pp < P1B; pp += 4){
      int n = min(lcnt[pp], DEPTH);
      int nf = n & ~(FCH - 1);
      if (nf > 0){
        int gb = 0;
        if (lane == 0) gb = atomicAdd(&gcnt[(beh * P1B + pp) * CSTR], nf);
        gb = __shfl(gb, 0);
        long long sb = (long long)(beh * P1B + pp) * CAP1;
        for (int k = lane; k < nf; k += 64)
          if (gb + k < CAP1) stg[sb + gb + k] = lbuf[pp][k];
        int res = n - nf;
        int2 t;
        if (lane < res) t = lbuf[pp][nf + lane];
        if (lane < res) lbuf[pp][lane] = t;
        if (lane == 0) lcnt[pp] = res;
      }
    }
    __syncthreads();
  }
  for (int pp = wv; pp < P1B; pp += 4){
    int n = min(lcnt[pp], DEPTH);
    if (n > 0){
      int gb = 0;
      if (lane == 0) gb = atomicAdd(&gcnt[(beh * P1B + pp) * CSTR], n);
      gb = __shfl(gb, 0);
      long long sb = (long long)(beh * P1B + pp) * CAP1;
      if (lane < n && gb + lane < CAP1) stg[sb + gb + lane] = lbuf[pp][lane];
    }
  }
}

// ---------------- hist3: LDS-private per-bucket histogram ------------------
__global__ __launch_bounds__(256) void k_hist3(const int* __restrict__ gcnt,
                                               const int2* __restrict__ stg,
                                               int* __restrict__ cnt){
  __shared__ int h[PR1];                     // 37.5 KB
  int bucket = blockIdx.x / HJ;
  int j = blockIdx.x - bucket * HJ;
  for (int i = threadIdx.x; i < PR1; i += 256) h[i] = 0;
  __syncthreads();
  int n = min(gcnt[bucket * CSTR], CAP1);
  const int2* st = stg + (long long)bucket * CAP1;
  int chunk = (n + HJ - 1) / HJ;
  int lo = j * chunk, hi = min(n, lo + chunk);
  for (int i = lo + threadIdx.x; i < hi; i += 256)
    atomicAdd(&h[(unsigned)st[i].x >> 18], 1);
  __syncthreads();
  int beh = bucket / P1B, part = bucket - beh * P1B;
  int* c = cnt + (long long)beh * NN + part * PR1;
  for (int i = threadIdx.x; i < PR1; i += 256){
    int v = h[i];
    if (v) atomicAdd(&c[i], v);
  }
}

// ---------------- scans (cnt -> rp, tp) ------------------------------------
__global__ __launch_bounds__(1024) void k_bsum(const int* __restrict__ cnt,
                                               int* __restrict__ bsum){
  int blk = blockIdx.x;
  int b = blk / CPB, ch = blk - b * CPB;
  const int* src = cnt + (long long)b * NN;
  int base = ch * SCAN_CHUNK + threadIdx.x * 4;
  int s = 0;
  #pragma unroll
  for (int k = 0; k < 4; ++k){
    int i = base + k;
    if (i < NN) s += src[i];
  }
  __shared__ int sd[1024];
  sd[threadIdx.x] = s;
  __syncthreads();
  for (int off = 512; off > 0; off >>= 1){
    if (threadIdx.x < off) sd[threadIdx.x] += sd[threadIdx.x + off];
    __syncthreads();
  }
  if (threadIdx.x == 0) bsum[blk] = sd[0];
}

__global__ __launch_bounds__(64) void k_bscan(const int* __restrict__ bsum,
                                              int* __restrict__ boff,
                                              int* __restrict__ rp){
  int b = threadIdx.x;
  if (b >= BB) return;
  int run = 0;
  for (int c = 0; c < CPB; ++c){
    boff[b * CPB + c] = run;
    run += bsum[b * CPB + c];
  }
  rp[(long long)b * (NN + 1) + NN] = run;
}

__global__ __launch_bounds__(1024) void k_scan2(const int* __restrict__ cnt,
                                                const int* __restrict__ boff,
                                                int* __restrict__ rp,
                                                int* __restrict__ tp){
  int blk = blockIdx.x;
  int b = blk / CPB, ch = blk - b * CPB;
  const int* src = cnt + (long long)b * NN;
  int* rpo = rp + (long long)b * (NN + 1);
  int* tpo = tp + (long long)b * NN;
  int base = ch * SCAN_CHUNK + threadIdx.x * 4;
  int v[4]; int tsum = 0;
  #pragma unroll
  for (int k = 0; k < 4; ++k){
    int i = base + k;
    v[k] = (i < NN) ? src[i] : 0;
    tsum += v[k];
  }
  __shared__ int sd[1024];
  sd[threadIdx.x] = tsum;
  __syncthreads();
  for (int off = 1; off < 1024; off <<= 1){
    int t = (threadIdx.x >= off) ? sd[threadIdx.x - off] : 0;
    __syncthreads();
    sd[threadIdx.x] += t;
    __syncthreads();
  }
  int excl = boff[blk] + sd[threadIdx.x] - tsum;
  #pragma unroll
  for (int k = 0; k < 4; ++k){
    int i = base + k;
    if (i < NN){ rpo[i] = excl; tpo[i] = excl; }
    excl += v[k];
  }
}

// ---------------- pass 2: ONE bucket per XCD per launch --------------------
__global__ __launch_bounds__(256) void k_p2(const int* __restrict__ gcnt,
                                            const int2* __restrict__ stg,
                                            int* __restrict__ tp,
                                            int2* __restrict__ cpk,
                                            int L){
  int x = blockIdx.x & 7;
  int j = blockIdx.x >> 3;                   // P2J chunks per bucket
  int bucket = L * 8 + x;
  int n = min(gcnt[bucket * CSTR], CAP1);
  int beh = bucket / P1B, part = bucket - beh * P1B;
  int rowbase = part * PR1;
  const int2* st = stg + (long long)bucket * CAP1;
  int* tpb = tp + (long long)beh * NN;
  int2* dst = cpk + (long long)beh * NNZE;
  int chunk = (n + P2J - 1) / P2J;
  int lo = j * chunk, hi = min(n, lo + chunk);
  for (int i = lo + threadIdx.x; i < hi; i += 256){
    int2 e = st[i];
    int row = rowbase + (int)((unsigned)e.x >> 18);
    int col = e.x & 0x3FFFF;
    int pos = atomicAdd(&tpb[row], 1);
    dst[pos] = make_int2(col, e.y);
  }
}

// ---------------- SpMM: bf16 gather table (128B/row), fp32 accumulate ------
#define GB(NK)                                                              \
  {                                                                         \
    int   c[NK]; float v[NK]; float x[NK];                                  \
    _Pragma("unroll")                                                       \
    for (int k = 0; k < NK; ++k){                                           \
      int2 q = pk[e + k];                                                   \
      c[k] = __builtin_amdgcn_readfirstlane(q.x);                           \
      v[k] = __int_as_float(__builtin_amdgcn_readfirstlane(q.y));           \
    }                                                                       \
    _Pragma("unroll")                                                       \
    for (int k = 0; k < NK; ++k){                                           \
      unsigned w = xb[(long long)c[k] * 32 + (lane >> 1)];                  \
      x[k] = __uint_as_float((lane & 1) ? (w & 0xFFFF0000u) : (w << 16));   \
    }                                                                       \
    _Pragma("unroll")                                                       \
    for (int k = 0; k < NK; ++k){                                           \
      if (k & 1) sB = fmaf(v[k], x[k], sB);                                 \
      else       sA = fmaf(v[k], x[k], sA);                                 \
    }                                                                       \
    e += NK;                                                                \
  }

template<int MODE>
__global__ __launch_bounds__(256) void k_spmmB(const int* __restrict__ rp,
                                               const int2* __restrict__ cpk,
                                               const unsigned* __restrict__ xb,
                                               const float* __restrict__ ue,
                                               const float* __restrict__ ie,
                                               unsigned* __restrict__ dstb,
                                               float* __restrict__ acc,
                                               int b){
  int row = blockIdx.x * (blockDim.x >> 6) + (threadIdx.x >> 6);  // < NN
  int lane = threadIdx.x & 63;
  row = __builtin_amdgcn_readfirstlane(row);
  const int* rpo = rp + (long long)b * (NN + 1);
  int s0 = __builtin_amdgcn_readfirstlane(rpo[row]);
  int s1 = __builtin_amdgcn_readfirstlane(rpo[row + 1]);
  const int2* pk = cpk + (long long)b * NNZE;
  float sA = 0.f, sB = 0.f;
  int e = s0;
  while (e + 16 <= s1) GB(16)
  if (e + 8 <= s1) GB(8)
  if (e + 4 <= s1) GB(4)
  if (e + 2 <= s1) GB(2)
  if (e < s1){
    int2 q = pk[e];
    int   c0 = __builtin_amdgcn_readfirstlane(q.x);
    float v0 = __int_as_float(__builtin_amdgcn_readfirstlane(q.y));
    unsigned w = xb[(long long)c0 * 32 + (lane >> 1)];
    float x0 = __uint_as_float((lane & 1) ? (w & 0xFFFF0000u) : (w << 16));
    sA = fmaf(v0, x0, sA);
  }
  float s = sA + sB;
  long long o = ((long long)b * NN + row) * 64 + lane;
  if (MODE == 0){
    float ego = (row < UCNT) ? ue[(long long)row * 64 + lane]
                             : ie[(long long)(row - UCNT) * 64 + lane];
    acc[o] = ego + s;
  } else {
    acc[o] += s;
  }
  if (MODE != 2){
    unsigned u = __float_as_uint(s);
    u += 0x7FFF + ((u >> 16) & 1);
    unsigned hb = u >> 16;                            // bf16 RN
    unsigned ot = (unsigned)__shfl_xor((int)hb, 1);
    if (!(lane & 1))
      dstb[(long long)row * 32 + (lane >> 1)] = hb | (ot << 16);
  }
}

// ---------------- attention: score — burst load, HEAD-OUTER, float4 weights -
// Avoids all three measured failure modes: R20 (3072 scalar LDS reads),
// R21 (strided float4 global loads, 2.5x refetch), R22 (48 live accumulators
// -> spill). Head-outer keeps hid[16] (16 regs); v[16] burst-loaded (64);
// weights read as ds_read_b128 broadcast (768 total).
__device__ __forceinline__ float fast_tanh(float x){
  float xc = fminf(fmaxf(x, -15.f), 15.f);
  float t = __expf(2.f * xc);
  return (t - 1.f) / (t + 1.f);
}

__global__ __launch_bounds__(256) void k_score(const float* __restrict__ acc,
                                               const float* __restrict__ W1,
                                               const float* __restrict__ W2,
                                               float* __restrict__ scbuf){
  __shared__ float4 sW1t[BB * 16 * 16];      // 12.3 KB; [(h*16+k)*16+c]
  __shared__ float  sW2[BB * 16];
  for (int i = threadIdx.x; i < BB * 16 * 16 * 4; i += blockDim.x){
    int j = i & 3, c = (i >> 2) & 15, k = (i >> 6) & 15, h = i >> 10;
    ((float*)&sW1t[(h * 16 + k) * 16 + c])[j] = W1[h * 1024 + (4 * c + j) * 16 + k];
  }
  if (threadIdx.x < BB * 16) sW2[threadIdx.x] = W2[threadIdx.x];
  __syncthreads();
  int t = blockIdx.x * blockDim.x + threadIdx.x;
  if (t >= BB * NN) return;
  int b = t / NN;
  int n = t - b * NN;

  const float4* src = (const float4*)(acc + ((long long)b * NN + n) * 64);
  float4 v[16];
  #pragma unroll
  for (int c = 0; c < 16; ++c){
    v[c] = src[c];
    v[c].x *= 0.25f; v[c].y *= 0.25f; v[c].z *= 0.25f; v[c].w *= 0.25f;
  }
  for (int h = 0; h < BB; ++h){              // head-outer: only hid[16] live
    float hid[16];
    #pragma unroll
    for (int k = 0; k < 16; ++k) hid[k] = 0.f;
    #pragma unroll
    for (int c = 0; c < 16; ++c){
      #pragma unroll
      for (int k = 0; k < 16; ++k){
        float4 w = sW1t[(h * 16 + k) * 16 + c];
        hid[k] += v[c].x * w.x + v[c].y * w.y + v[c].z * w.z + v[c].w * w.w;
      }
    }
    float s = 0.f;
    #pragma unroll
    for (int k = 0; k < 16; ++k) s += fast_tanh(hid[k]) * sW2[h * 16 + k];
    scbuf[(long long)n * 9 + h * 3 + b] = s;
  }
}

// ---------------- attention: softmax + weighted sum (thread per (n, c4)) ---
__global__ __launch_bounds__(256) void k_att2(const float* __restrict__ acc,
                                              const float* __restrict__ scbuf,
                                              float* __restrict__ out){
  int t = blockIdx.x * blockDim.x + threadIdx.x;   // NN*16 threads
  int n = t >> 4;
  int c = t & 15;
  if (n >= NN) return;
  float sc[9];
  #pragma unroll
  for (int i = 0; i < 9; ++i) sc[i] = scbuf[(long long)n * 9 + i];

  float a[BB][BB];
  #pragma unroll
  for (int h = 0; h < BB; ++h){
    float s0 = sc[h * 3], s1 = sc[h * 3 + 1], s2 = sc[h * 3 + 2];
    float m = fmaxf(fmaxf(s0, s1), s2);
    float e0 = __expf(s0 - m), e1 = __expf(s1 - m), e2 = __expf(s2 - m);
    float inv = 1.f / (e0 + e1 + e2);
    a[h][0] = e0 * inv; a[h][1] = e1 * inv; a[h][2] = e2 * inv;
  }
  float4 x0 = ((const float4*)(acc + ((long long)0 * NN + n) * 64))[c];
  float4 x1 = ((const float4*)(acc + ((long long)1 * NN + n) * 64))[c];
  float4 x2 = ((const float4*)(acc + ((long long)2 * NN + n) * 64))[c];
  x0.x *= 0.25f; x0.y *= 0.25f; x0.z *= 0.25f; x0.w *= 0.25f;
  x1.x *= 0.25f; x1.y *= 0.25f; x1.z *= 0.25f; x1.w *= 0.25f;
  x2.x *= 0.25f; x2.y *= 0.25f; x2.z *= 0.25f; x2.w *= 0.25f;
  #pragma unroll
  for (int h = 0; h < BB; ++h){
    float4 o;
    o.x = a[h][0]*x0.x + a[h][1]*x1.x + a[h][2]*x2.x;
    o.y = a[h][0]*x0.y + a[h][1]*x1.y + a[h][2]*x2.y;
    o.z = a[h][0]*x0.z + a[h][1]*x1.z + a[h][2]*x2.z;
    o.w = a[h][0]*x0.w + a[h][1]*x1.w + a[h][2]*x2.w;
    long long dst;
    if (n < UCNT) dst = ((long long)h * UCNT + n) * 64;
    else          dst = (long long)BB * UCNT * 64 + ((long long)h * ICNT + (n - UCNT)) * 64;
    ((float4*)(out + dst))[c] = o;
  }
}

// ---------------- launch ---------------------------------------------------
extern "C" void kernel_launch(void* const* d_in, const int* in_sizes, int n_in,
                              void* d_out, int out_size, void* d_ws, size_t ws_size,
                              hipStream_t stream){
  const float* ue   = (const float*)d_in[0];
  const float* ie   = (const float*)d_in[1];
  const float* W1   = (const float*)d_in[2];
  const float* W2   = (const float*)d_in[3];
  const float* vals = (const float*)d_in[4];
  const int*   rows = (const int*)d_in[5];
  const int*   cols = (const int*)d_in[6];
  float* out = (float*)d_out;

  char* ws = (char*)d_ws;
  size_t off = 0;
  auto alloc = [&](size_t bytes){ void* p = ws + off; off += (bytes + 255) & ~(size_t)255; return p; };
  float*    acc   = (float*)alloc((size_t)BB * NN * 64 * 4);   // 115.2 MB
  int2*     cpk   = (int2*)alloc((size_t)BB * NNZE * 8);       // 57.6 MB
  int2*     stg   = (int2*)alloc((size_t)NBKT * CAP1 * 8);     // 59.9 MB
  unsigned* egob  = (unsigned*)alloc((size_t)NN * 32 * 4);     // 19.2 MB
  unsigned* layb0 = (unsigned*)alloc((size_t)NN * 32 * 4);     // 19.2 MB
  unsigned* layb1 = (unsigned*)alloc((size_t)NN * 32 * 4);     // 19.2 MB
  int*      rp    = (int*)alloc((size_t)BB * (NN + 1) * 4);
  int*      tp    = (int*)alloc((size_t)BB * NN * 4);
  int*      cnt   = (int*)alloc((size_t)BB * NN * 4);
  int*      bsum  = (int*)alloc((size_t)BB * CPB * 4);
  int*      boff  = (int*)alloc((size_t)BB * CPB * 4);
  int*      gcnt  = (int*)alloc((size_t)NBKT * CSTR * 4);
  float*    scbuf = (float*)alloc((size_t)NN * 9 * 4);         // 5.4 MB
  (void)ws_size; (void)in_sizes; (void)n_in; (void)out_size;

  // CSR build + ego bf16 table
  k_zero2<<<(BB * NN + NBKT * CSTR + 255) / 256, 256, 0, stream>>>(cnt, gcnt);
  k_cvt<<<(int)(((long long)NN * 32 + 255) / 256), 256, 0, stream>>>(ue, ie, egob);
  k_p1<<<BB * P1BLK, 256, 0, stream>>>(rows, cols, vals, gcnt, stg);
  k_hist3<<<NBKT * HJ, 256, 0, stream>>>(gcnt, stg, cnt);
  k_bsum<<<BB * CPB, 1024, 0, stream>>>(cnt, bsum);
  k_bscan<<<1, 64, 0, stream>>>(bsum, boff, rp);
  k_scan2<<<BB * CPB, 1024, 0, stream>>>(cnt, boff, rp, tp);
  for (int L = 0; L < 6; ++L)
    k_p2<<<8 * P2J, 256, 0, stream>>>(gcnt, stg, tp, cpk, L);

  // propagate: one behavior per dispatch; bf16 gather tables, fp32 acc
  for (int b = 0; b < BB; ++b){
    k_spmmB<0><<<NN / 4, 256, 0, stream>>>(rp, cpk, egob,  ue, ie, layb0, acc, b);
    k_spmmB<1><<<NN / 4, 256, 0, stream>>>(rp, cpk, layb0, ue, ie, layb1, acc, b);
    k_spmmB<2><<<NN / 4, 256, 0, stream>>>(rp, cpk, layb1, ue, ie, nullptr, acc, b);
  }
  // attention: parallel score pass + streaming combine pass
  k_score<<<(BB * NN + 255) / 256, 256, 0, stream>>>(acc, W1, W2, scbuf);
  k_att2<<<(NN * 16) / 256, 256, 0, stream>>>(acc, scbuf, out);
}

// Round 24
// 1118.836 us; speedup vs baseline: 1.0415x; 1.0078x over previous
//
#include <hip/hip_runtime.h>

#define UCNT 100000
#define ICNT 50000
#define BB   3
#define NNZE 2400000
#define NN   150000   // UCNT + ICNT

#define P1B   16                  // coarse parts per behavior
#define PR1   9375                // rows per part  (16*9375 = 150000)
#define CAP1  156000              // bucket capacity (mean 150000 + 16 sigma)
#define NBKT  (BB * P1B)          // 48 buckets
#define DEPTH 192                 // fifo depth (63 residue + ~32 mean burst; >17 sigma) + overflow guard
#define FCH   64                  // flush chunk (64 * 8B = 512B contiguous)
#define P1BLK 375                 // blocks per behavior (375 * 6400 = 2400000)
#define P1CH  6400                // edges per block (13 rounds of 512, last=256)
#define CSTR  16                  // counter stride (one 64B line each)
#define HJ    8                   // hist blocks per bucket
#define P2J   128                 // chunks per bucket in p2

#define SCAN_CHUNK 4096
#define CPB ((NN + SCAN_CHUNK - 1) / SCAN_CHUNK)

// ---------------- fused zero: cnt + gcnt ------------------------------------
__global__ __launch_bounds__(256) void k_zero2(int* __restrict__ cnt,
                                               int* __restrict__ gcnt){
  long long i = (long long)blockIdx.x * blockDim.x + threadIdx.x;
  if (i < (long long)BB * NN) cnt[i] = 0;
  long long j = i - (long long)BB * NN;
  if (j >= 0 && j < NBKT * CSTR) gcnt[j] = 0;
}

// ---------------- ego -> packed bf16 table (one copy, behavior-shared) -----
__global__ __launch_bounds__(256) void k_cvt(const float* __restrict__ ue,
                                             const float* __restrict__ ie,
                                             unsigned* __restrict__ egob){
  long long w = (long long)blockIdx.x * blockDim.x + threadIdx.x; // u32 index
  if (w >= (long long)NN * 32) return;
  long long n = w >> 5;
  int pr = (int)(w & 31);
  const float* src = (n < UCNT) ? (ue + n * 64) : (ie + (n - UCNT) * 64);
  float2 v = *(const float2*)(src + pr * 2);
  unsigned a = __float_as_uint(v.x); a += 0x7FFF + ((a >> 16) & 1);
  unsigned b = __float_as_uint(v.y); b += 0x7FFF + ((b >> 16) & 1);
  egob[w] = (a >> 16) | (b & 0xFFFF0000u);
}

// ---------------- pass 1: LDS bin, 512 edges/round (13 rounds) -------------
__global__ __launch_bounds__(256) void k_p1(const int* __restrict__ rows,
                                            const int* __restrict__ cols,
                                            const float* __restrict__ vals,
                                            int* __restrict__ gcnt,
                                            int2* __restrict__ stg){
  __shared__ int2 lbuf[P1B][DEPTH];        // 24 KB
  __shared__ int  lcnt[P1B];
  int tid = threadIdx.x, lane = tid & 63, wv = tid >> 6;
  int beh = blockIdx.x / P1BLK;
  int blk = blockIdx.x - beh * P1BLK;
  long long ebase = (long long)beh * NNZE + (long long)blk * P1CH;
  if (tid < P1B) lcnt[tid] = 0;
  __syncthreads();

  for (int r = 0; r < 13; ++r){
    int off = r * 512 + tid * 2;
    if (off < P1CH){
      long long i = ebase + off;
      int2  rr = *(const int2*)(rows + i);
      int2  cc = *(const int2*)(cols + i);
      float2 vv = *(const float2*)(vals + i);
      #pragma unroll
      for (int k = 0; k < 2; ++k){
        int row = k ? rr.y : rr.x;
        int col = k ? cc.y : cc.x;
        float val = k ? vv.y : vv.x;
        int part = row / PR1;
        int2 ent = make_int2(((row - part * PR1) << 18) | col,
                             __float_as_int(val));
        int p = atomicAdd(&lcnt[part], 1);
        if (p < DEPTH){
          lbuf[part][p] = ent;
        } else {                                   // ~never: direct global
          int gb = atomicAdd(&gcnt[(beh * P1B + part) * CSTR], 1);
          if (gb < CAP1)
            stg[(long long)(beh * P1B + part) * CAP1 + gb] = ent;
        }
      }
    }
    __syncthreads();
    for (int pp = wv; pp < P1B; pp += 4){
      int n = min(lcnt[pp], DEPTH);
      int nf = n & ~(FCH - 1);
      if (nf > 0){
        int gb = 0;
        if (lane == 0) gb = atomicAdd(&gcnt[(beh * P1B + pp) * CSTR], nf);
        gb = __shfl(gb, 0);
        long long sb = (long long)(beh * P1B + pp) * CAP1;
        for (int k = lane; k < nf; k += 64)
          if (gb + k < CAP1) stg[sb + gb + k] = lbuf[pp][k];
        int res = n - nf;
        int2 t;
        if (lane < res) t = lbuf[pp][nf + lane];
        if (lane < res) lbuf[pp][lane] = t;
        if (lane == 0) lcnt[pp] = res;
      }
    }
    __syncthreads();
  }
  for (int pp = wv; pp < P1B; pp += 4){
    int n = min(lcnt[pp], DEPTH);
    if (n > 0){
      int gb = 0;
      if (lane == 0) gb = atomicAdd(&gcnt[(beh * P1B + pp) * CSTR], n);
      gb = __shfl(gb, 0);
      long long sb = (long long)(beh * P1B + pp) * CAP1;
      if (lane < n && gb + lane < CAP1) stg[sb + gb + lane] = lbuf[pp][lane];
    }
  }
}

// ---------------- hist3: LDS-private per-bucket histogram ------------------
__global__ __launch_bounds__(256) void k_hist3(const int* __restrict__ gcnt,
                                               const int2* __restrict__ stg,
                                               int* __restrict__ cnt){
  __shared__ int h[PR1];                     // 37.5 KB
  int bucket = blockIdx.x / HJ;
  int j = blockIdx.x - bucket * HJ;
  for (int i = threadIdx.x; i < PR1; i += 256) h[i] = 0;
  __syncthreads();
  int n = min(gcnt[bucket * CSTR], CAP1);
  const int2* st = stg + (long long)bucket * CAP1;
  int chunk = (n + HJ - 1) / HJ;
  int lo = j * chunk, hi = min(n, lo + chunk);
  for (int i = lo + threadIdx.x; i < hi; i += 256)
    atomicAdd(&h[(unsigned)st[i].x >> 18], 1);
  __syncthreads();
  int beh = bucket / P1B, part = bucket - beh * P1B;
  int* c = cnt + (long long)beh * NN + part * PR1;
  for (int i = threadIdx.x; i < PR1; i += 256){
    int v = h[i];
    if (v) atomicAdd(&c[i], v);
  }
}

// ---------------- scans (cnt -> rp, tp) ------------------------------------
__global__ __launch_bounds__(1024) void k_bsum(const int* __restrict__ cnt,
                                               int* __restrict__ bsum){
  int blk = blockIdx.x;
  int b = blk / CPB, ch = blk - b * CPB;
  const int* src = cnt + (long long)b * NN;
  int base = ch * SCAN_CHUNK + threadIdx.x * 4;
  int s = 0;
  #pragma unroll
  for (int k = 0; k < 4; ++k){
    int i = base + k;
    if (i < NN) s += src[i];
  }
  __shared__ int sd[1024];
  sd[threadIdx.x] = s;
  __syncthreads();
  for (int off = 512; off > 0; off >>= 1){
    if (threadIdx.x < off) sd[threadIdx.x] += sd[threadIdx.x + off];
    __syncthreads();
  }
  if (threadIdx.x == 0) bsum[blk] = sd[0];
}

__global__ __launch_bounds__(64) void k_bscan(const int* __restrict__ bsum,
                                              int* __restrict__ boff,
                                              int* __restrict__ rp){
  int b = threadIdx.x;
  if (b >= BB) return;
  int run = 0;
  for (int c = 0; c < CPB; ++c){
    boff[b * CPB + c] = run;
    run += bsum[b * CPB + c];
  }
  rp[(long long)b * (NN + 1) + NN] = run;
}

__global__ __launch_bounds__(1024) void k_scan2(const int* __restrict__ cnt,
                                                const int* __restrict__ boff,
                                                int* __restrict__ rp,
                                                int* __restrict__ tp){
  int blk = blockIdx.x;
  int b = blk / CPB, ch = blk - b * CPB;
  const int* src = cnt + (long long)b * NN;
  int* rpo = rp + (long long)b * (NN + 1);
  int* tpo = tp + (long long)b * NN;
  int base = ch * SCAN_CHUNK + threadIdx.x * 4;
  int v[4]; int tsum = 0;
  #pragma unroll
  for (int k = 0; k < 4; ++k){
    int i = base + k;
    v[k] = (i < NN) ? src[i] : 0;
    tsum += v[k];
  }
  __shared__ int sd[1024];
  sd[threadIdx.x] = tsum;
  __syncthreads();
  for (int off = 1; off < 1024; off <<= 1){
    int t = (threadIdx.x >= off) ? sd[threadIdx.x - off] : 0;
    __syncthreads();
    sd[threadIdx.x] += t;
    __syncthreads();
  }
  int excl = boff[blk] + sd[threadIdx.x] - tsum;
  #pragma unroll
  for (int k = 0; k < 4; ++k){
    int i = base + k;
    if (i < NN){ rpo[i] = excl; tpo[i] = excl; }
    excl += v[k];
  }
}

// ---------------- pass 2: ONE bucket per XCD per launch --------------------
__global__ __launch_bounds__(256) void k_p2(const int* __restrict__ gcnt,
                                            const int2* __restrict__ stg,
                                            int* __restrict__ tp,
                                            int2* __restrict__ cpk,
                                            int L){
  int x = blockIdx.x & 7;
  int j = blockIdx.x >> 3;                   // P2J chunks per bucket
  int bucket = L * 8 + x;
  int n = min(gcnt[bucket * CSTR], CAP1);
  int beh = bucket / P1B, part = bucket - beh * P1B;
  int rowbase = part * PR1;
  const int2* st = stg + (long long)bucket * CAP1;
  int* tpb = tp + (long long)beh * NN;
  int2* dst = cpk + (long long)beh * NNZE;
  int chunk = (n + P2J - 1) / P2J;
  int lo = j * chunk, hi = min(n, lo + chunk);
  for (int i = lo + threadIdx.x; i < hi; i += 256){
    int2 e = st[i];
    int row = rowbase + (int)((unsigned)e.x >> 18);
    int col = e.x & 0x3FFFF;
    int pos = atomicAdd(&tpb[row], 1);
    dst[pos] = make_int2(col, e.y);
  }
}

// ---------------- SpMM: bf16 gather table (128B/row), fp32 accumulate ------
#define GB(NK)                                                              \
  {                                                                         \
    int   c[NK]; float v[NK]; float x[NK];                                  \
    _Pragma("unroll")                                                       \
    for (int k = 0; k < NK; ++k){                                           \
      int2 q = pk[e + k];                                                   \
      c[k] = __builtin_amdgcn_readfirstlane(q.x);                           \
      v[k] = __int_as_float(__builtin_amdgcn_readfirstlane(q.y));           \
    }                                                                       \
    _Pragma("unroll")                                                       \
    for (int k = 0; k < NK; ++k){                                           \
      unsigned w = xb[(long long)c[k] * 32 + (lane >> 1)];                  \
      x[k] = __uint_as_float((lane & 1) ? (w & 0xFFFF0000u) : (w << 16));   \
    }                                                                       \
    _Pragma("unroll")                                                       \
    for (int k = 0; k < NK; ++k){                                           \
      if (k & 1) sB = fmaf(v[k], x[k], sB);                                 \
      else       sA = fmaf(v[k], x[k], sA);                                 \
    }                                                                       \
    e += NK;                                                                \
  }

template<int MODE>
__global__ __launch_bounds__(256) void k_spmmB(const int* __restrict__ rp,
                                               const int2* __restrict__ cpk,
                                               const unsigned* __restrict__ xb,
                                               const float* __restrict__ ue,
                                               const float* __restrict__ ie,
                                               unsigned* __restrict__ dstb,
                                               float* __restrict__ acc,
                                               int b){
  int row = blockIdx.x * (blockDim.x >> 6) + (threadIdx.x >> 6);  // < NN
  int lane = threadIdx.x & 63;
  row = __builtin_amdgcn_readfirstlane(row);
  const int* rpo = rp + (long long)b * (NN + 1);
  int s0 = __builtin_amdgcn_readfirstlane(rpo[row]);
  int s1 = __builtin_amdgcn_readfirstlane(rpo[row + 1]);
  const int2* pk = cpk + (long long)b * NNZE;
  float sA = 0.f, sB = 0.f;
  int e = s0;
  while (e + 16 <= s1) GB(16)
  if (e + 8 <= s1) GB(8)
  if (e + 4 <= s1) GB(4)
  if (e + 2 <= s1) GB(2)
  if (e < s1){
    int2 q = pk[e];
    int   c0 = __builtin_amdgcn_readfirstlane(q.x);
    float v0 = __int_as_float(__builtin_amdgcn_readfirstlane(q.y));
    unsigned w = xb[(long long)c0 * 32 + (lane >> 1)];
    float x0 = __uint_as_float((lane & 1) ? (w & 0xFFFF0000u) : (w << 16));
    sA = fmaf(v0, x0, sA);
  }
  float s = sA + sB;
  long long o = ((long long)b * NN + row) * 64 + lane;
  if (MODE == 0){
    float ego = (row < UCNT) ? ue[(long long)row * 64 + lane]
                             : ie[(long long)(row - UCNT) * 64 + lane];
    acc[o] = ego + s;
  } else {
    acc[o] += s;
  }
  if (MODE != 2){
    unsigned u = __float_as_uint(s);
    u += 0x7FFF + ((u >> 16) & 1);
    unsigned hb = u >> 16;                            // bf16 RN
    unsigned ot = (unsigned)__shfl_xor((int)hb, 1);
    if (!(lane & 1))
      dstb[(long long)row * 32 + (lane >> 1)] = hb | (ot << 16);
  }
}

// ---------------- attention: score pass (R20 proven version) ---------------
// Thread per (behavior, node); burst row load into v[16]; scalar LDS weight
// reads (stride-16 layout) with head-outer hid[16]. Best measured of 4
// variants (104 us): R21 float4-c-outer refetched 2.5x from HBM, R22
// spilled 48 accumulators, R23 b128-broadcast had worse issue efficiency.
__device__ __forceinline__ float fast_tanh(float x){
  float xc = fminf(fmaxf(x, -15.f), 15.f);
  float t = __expf(2.f * xc);
  return (t - 1.f) / (t + 1.f);
}

__global__ __launch_bounds__(256) void k_score(const float* __restrict__ acc,
                                               const float* __restrict__ W1,
                                               const float* __restrict__ W2,
                                               float* __restrict__ scbuf){
  __shared__ float sW1[BB * 64 * 16];
  __shared__ float sW2[BB * 16];
  for (int i = threadIdx.x; i < BB * 64 * 16; i += blockDim.x) sW1[i] = W1[i];
  if (threadIdx.x < BB * 16) sW2[threadIdx.x] = W2[threadIdx.x];
  __syncthreads();
  int t = blockIdx.x * blockDim.x + threadIdx.x;
  if (t >= BB * NN) return;
  int b = t / NN;
  int n = t - b * NN;

  const float4* src = (const float4*)(acc + ((long long)b * NN + n) * 64);
  float4 v[16];
  #pragma unroll
  for (int c = 0; c < 16; ++c){
    v[c] = src[c];
    v[c].x *= 0.25f; v[c].y *= 0.25f; v[c].z *= 0.25f; v[c].w *= 0.25f;
  }
  for (int h = 0; h < BB; ++h){
    float hid[16];
    #pragma unroll
    for (int k = 0; k < 16; ++k) hid[k] = 0.f;
    #pragma unroll
    for (int c = 0; c < 16; ++c){
      const float* w = &sW1[h * 1024 + c * 64];
      #pragma unroll
      for (int k = 0; k < 16; ++k){
        hid[k] += v[c].x * w[k] + v[c].y * w[16 + k]
                + v[c].z * w[32 + k] + v[c].w * w[48 + k];
      }
    }
    float s = 0.f;
    #pragma unroll
    for (int k = 0; k < 16; ++k) s += fast_tanh(hid[k]) * sW2[h * 16 + k];
    scbuf[(long long)n * 9 + h * 3 + b] = s;
  }
}

// ---------------- attention: softmax + weighted sum (thread per (n, c4)) ---
__global__ __launch_bounds__(256) void k_att2(const float* __restrict__ acc,
                                              const float* __restrict__ scbuf,
                                              float* __restrict__ out){
  int t = blockIdx.x * blockDim.x + threadIdx.x;   // NN*16 threads
  int n = t >> 4;
  int c = t & 15;
  if (n >= NN) return;
  float sc[9];
  #pragma unroll
  for (int i = 0; i < 9; ++i) sc[i] = scbuf[(long long)n * 9 + i];

  float a[BB][BB];
  #pragma unroll
  for (int h = 0; h < BB; ++h){
    float s0 = sc[h * 3], s1 = sc[h * 3 + 1], s2 = sc[h * 3 + 2];
    float m = fmaxf(fmaxf(s0, s1), s2);
    float e0 = __expf(s0 - m), e1 = __expf(s1 - m), e2 = __expf(s2 - m);
    float inv = 1.f / (e0 + e1 + e2);
    a[h][0] = e0 * inv; a[h][1] = e1 * inv; a[h][2] = e2 * inv;
  }
  float4 x0 = ((const float4*)(acc + ((long long)0 * NN + n) * 64))[c];
  float4 x1 = ((const float4*)(acc + ((long long)1 * NN + n) * 64))[c];
  float4 x2 = ((const float4*)(acc + ((long long)2 * NN + n) * 64))[c];
  x0.x *= 0.25f; x0.y *= 0.25f; x0.z *= 0.25f; x0.w *= 0.25f;
  x1.x *= 0.25f; x1.y *= 0.25f; x1.z *= 0.25f; x1.w *= 0.25f;
  x2.x *= 0.25f; x2.y *= 0.25f; x2.z *= 0.25f; x2.w *= 0.25f;
  #pragma unroll
  for (int h = 0; h < BB; ++h){
    float4 o;
    o.x = a[h][0]*x0.x + a[h][1]*x1.x + a[h][2]*x2.x;
    o.y = a[h][0]*x0.y + a[h][1]*x1.y + a[h][2]*x2.y;
    o.z = a[h][0]*x0.z + a[h][1]*x1.z + a[h][2]*x2.z;
    o.w = a[h][0]*x0.w + a[h][1]*x1.w + a[h][2]*x2.w;
    long long dst;
    if (n < UCNT) dst = ((long long)h * UCNT + n) * 64;
    else          dst = (long long)BB * UCNT * 64 + ((long long)h * ICNT + (n - UCNT)) * 64;
    ((float4*)(out + dst))[c] = o;
  }
}

// ---------------- launch ---------------------------------------------------
extern "C" void kernel_launch(void* const* d_in, const int* in_sizes, int n_in,
                              void* d_out, int out_size, void* d_ws, size_t ws_size,
                              hipStream_t stream){
  const float* ue   = (const float*)d_in[0];
  const float* ie   = (const float*)d_in[1];
  const float* W1   = (const float*)d_in[2];
  const float* W2   = (const float*)d_in[3];
  const float* vals = (const float*)d_in[4];
  const int*   rows = (const int*)d_in[5];
  const int*   cols = (const int*)d_in[6];
  float* out = (float*)d_out;

  char* ws = (char*)d_ws;
  size_t off = 0;
  auto alloc = [&](size_t bytes){ void* p = ws + off; off += (bytes + 255) & ~(size_t)255; return p; };
  float*    acc   = (float*)alloc((size_t)BB * NN * 64 * 4);   // 115.2 MB
  int2*     cpk   = (int2*)alloc((size_t)BB * NNZE * 8);       // 57.6 MB
  int2*     stg   = (int2*)alloc((size_t)NBKT * CAP1 * 8);     // 59.9 MB
  unsigned* egob  = (unsigned*)alloc((size_t)NN * 32 * 4);     // 19.2 MB
  unsigned* layb0 = (unsigned*)alloc((size_t)NN * 32 * 4);     // 19.2 MB
  unsigned* layb1 = (unsigned*)alloc((size_t)NN * 32 * 4);     // 19.2 MB
  int*      rp    = (int*)alloc((size_t)BB * (NN + 1) * 4);
  int*      tp    = (int*)alloc((size_t)BB * NN * 4);
  int*      cnt   = (int*)alloc((size_t)BB * NN * 4);
  int*      bsum  = (int*)alloc((size_t)BB * CPB * 4);
  int*      boff  = (int*)alloc((size_t)BB * CPB * 4);
  int*      gcnt  = (int*)alloc((size_t)NBKT * CSTR * 4);
  float*    scbuf = (float*)alloc((size_t)NN * 9 * 4);         // 5.4 MB
  (void)ws_size; (void)in_sizes; (void)n_in; (void)out_size;

  // CSR build + ego bf16 table
  k_zero2<<<(BB * NN + NBKT * CSTR + 255) / 256, 256, 0, stream>>>(cnt, gcnt);
  k_cvt<<<(int)(((long long)NN * 32 + 255) / 256), 256, 0, stream>>>(ue, ie, egob);
  k_p1<<<BB * P1BLK, 256, 0, stream>>>(rows, cols, vals, gcnt, stg);
  k_hist3<<<NBKT * HJ, 256, 0, stream>>>(gcnt, stg, cnt);
  k_bsum<<<BB * CPB, 1024, 0, stream>>>(cnt, bsum);
  k_bscan<<<1, 64, 0, stream>>>(bsum, boff, rp);
  k_scan2<<<BB * CPB, 1024, 0, stream>>>(cnt, boff, rp, tp);
  for (int L = 0; L < 6; ++L)
    k_p2<<<8 * P2J, 256, 0, stream>>>(gcnt, stg, tp, cpk, L);

  // propagate: one behavior per dispatch; bf16 gather tables, fp32 acc
  for (int b = 0; b < BB; ++b){
    k_spmmB<0><<<NN / 4, 256, 0, stream>>>(rp, cpk, egob,  ue, ie, layb0, acc, b);
    k_spmmB<1><<<NN / 4, 256, 0, stream>>>(rp, cpk, layb0, ue, ie, layb1, acc, b);
    k_spmmB<2><<<NN / 4, 256, 0, stream>>>(rp, cpk, layb1, ue, ie, nullptr, acc, b);
  }
  // attention: parallel score pass + streaming combine pass
  k_score<<<(BB * NN + 255) / 256, 256, 0, stream>>>(acc, W1, W2, scbuf);
  k_att2<<<(NN * 16) / 256, 256, 0, stream>>>(acc, scbuf, out);
}

// Round 25
// 1053.557 us; speedup vs baseline: 1.1060x; 1.0620x over previous
//
#include <hip/hip_runtime.h>

#define UCNT 100000
#define ICNT 50000
#define BB   3
#define NNZE 2400000
#define NN   150000   // UCNT + ICNT

#define P1B   16                  // coarse parts per behavior
#define PR1   9375                // rows per part  (16*9375 = 150000)
#define CAP1  156000              // bucket capacity (mean 150000 + 16 sigma)
#define NBKT  (BB * P1B)          // 48 buckets
#define DEPTH 192                 // fifo depth (63 residue + ~32 mean burst) + overflow guard
#define FCH   64                  // flush chunk (64 * 8B = 512B contiguous)
#define P1BLK 375                 // blocks per behavior (375 * 6400 = 2400000)
#define P1CH  6400                // edges per block (13 rounds of 512, last=256)
#define CSTR  16                  // counter stride (one 64B line each)
#define HJ    8                   // hist blocks per bucket
#define P2J   128                 // chunks per bucket in p2

#define SCAN_CHUNK 4096
#define CPB ((NN + SCAN_CHUNK - 1) / SCAN_CHUNK)

__device__ __forceinline__ float blo(unsigned u){ return __uint_as_float(u << 16); }
__device__ __forceinline__ float bhi(unsigned u){ return __uint_as_float(u & 0xFFFF0000u); }

// ---------------- fused zero: cnt + gcnt ------------------------------------
__global__ __launch_bounds__(256) void k_zero2(int* __restrict__ cnt,
                                               int* __restrict__ gcnt){
  long long i = (long long)blockIdx.x * blockDim.x + threadIdx.x;
  if (i < (long long)BB * NN) cnt[i] = 0;
  long long j = i - (long long)BB * NN;
  if (j >= 0 && j < NBKT * CSTR) gcnt[j] = 0;
}

// ---------------- ego -> packed bf16 table (one copy, behavior-shared) -----
__global__ __launch_bounds__(256) void k_cvt(const float* __restrict__ ue,
                                             const float* __restrict__ ie,
                                             unsigned* __restrict__ egob){
  long long w = (long long)blockIdx.x * blockDim.x + threadIdx.x; // u32 index
  if (w >= (long long)NN * 32) return;
  long long n = w >> 5;
  int pr = (int)(w & 31);
  const float* src = (n < UCNT) ? (ue + n * 64) : (ie + (n - UCNT) * 64);
  float2 v = *(const float2*)(src + pr * 2);
  unsigned a = __float_as_uint(v.x); a += 0x7FFF + ((a >> 16) & 1);
  unsigned b = __float_as_uint(v.y); b += 0x7FFF + ((b >> 16) & 1);
  egob[w] = (a >> 16) | (b & 0xFFFF0000u);
}

// ---------------- pass 1: LDS bin, 512 edges/round (13 rounds) -------------
__global__ __launch_bounds__(256) void k_p1(const int* __restrict__ rows,
                                            const int* __restrict__ cols,
                                            const float* __restrict__ vals,
                                            int* __restrict__ gcnt,
                                            int2* __restrict__ stg){
  __shared__ int2 lbuf[P1B][DEPTH];        // 24 KB
  __shared__ int  lcnt[P1B];
  int tid = threadIdx.x, lane = tid & 63, wv = tid >> 6;
  int beh = blockIdx.x / P1BLK;
  int blk = blockIdx.x - beh * P1BLK;
  long long ebase = (long long)beh * NNZE + (long long)blk * P1CH;
  if (tid < P1B) lcnt[tid] = 0;
  __syncthreads();

  for (int r = 0; r < 13; ++r){
    int off = r * 512 + tid * 2;
    if (off < P1CH){
      long long i = ebase + off;
      int2  rr = *(const int2*)(rows + i);
      int2  cc = *(const int2*)(cols + i);
      float2 vv = *(const float2*)(vals + i);
      #pragma unroll
      for (int k = 0; k < 2; ++k){
        int row = k ? rr.y : rr.x;
        int col = k ? cc.y : cc.x;
        float val = k ? vv.y : vv.x;
        int part = row / PR1;
        int2 ent = make_int2(((row - part * PR1) << 18) | col,
                             __float_as_int(val));
        int p = atomicAdd(&lcnt[part], 1);
        if (p < DEPTH){
          lbuf[part][p] = ent;
        } else {                                   // ~never: direct global
          int gb = atomicAdd(&gcnt[(beh * P1B + part) * CSTR], 1);
          if (gb < CAP1)
            stg[(long long)(beh * P1B + part) * CAP1 + gb] = ent;
        }
      }
    }
    __syncthreads();
    for (int pp = wv; pp < P1B; pp += 4){
      int n = min(lcnt[pp], DEPTH);
      int nf = n & ~(FCH - 1);
      if (nf > 0){
        int gb = 0;
        if (lane == 0) gb = atomicAdd(&gcnt[(beh * P1B + pp) * CSTR], nf);
        gb = __shfl(gb, 0);
        long long sb = (long long)(beh * P1B + pp) * CAP1;
        for (int k = lane; k < nf; k += 64)
          if (gb + k < CAP1) stg[sb + gb + k] = lbuf[pp][k];
        int res = n - nf;
        int2 t;
        if (lane < res) t = lbuf[pp][nf + lane];
        if (lane < res) lbuf[pp][lane] = t;
        if (lane == 0) lcnt[pp] = res;
      }
    }
    __syncthreads();
  }
  for (int pp = wv; pp < P1B; pp += 4){
    int n = min(lcnt[pp], DEPTH);
    if (n > 0){
      int gb = 0;
      if (lane == 0) gb = atomicAdd(&gcnt[(beh * P1B + pp) * CSTR], n);
      gb = __shfl(gb, 0);
      long long sb = (long long)(beh * P1B + pp) * CAP1;
      if (lane < n && gb + lane < CAP1) stg[sb + gb + lane] = lbuf[pp][lane];
    }
  }
}

// ---------------- hist3: LDS-private per-bucket histogram ------------------
__global__ __launch_bounds__(256) void k_hist3(const int* __restrict__ gcnt,
                                               const int2* __restrict__ stg,
                                               int* __restrict__ cnt){
  __shared__ int h[PR1];                     // 37.5 KB
  int bucket = blockIdx.x / HJ;
  int j = blockIdx.x - bucket * HJ;
  for (int i = threadIdx.x; i < PR1; i += 256) h[i] = 0;
  __syncthreads();
  int n = min(gcnt[bucket * CSTR], CAP1);
  const int2* st = stg + (long long)bucket * CAP1;
  int chunk = (n + HJ - 1) / HJ;
  int lo = j * chunk, hi = min(n, lo + chunk);
  for (int i = lo + threadIdx.x; i < hi; i += 256)
    atomicAdd(&h[(unsigned)st[i].x >> 18], 1);
  __syncthreads();
  int beh = bucket / P1B, part = bucket - beh * P1B;
  int* c = cnt + (long long)beh * NN + part * PR1;
  for (int i = threadIdx.x; i < PR1; i += 256){
    int v = h[i];
    if (v) atomicAdd(&c[i], v);
  }
}

// ---------------- scans (cnt -> rp, tp) ------------------------------------
__global__ __launch_bounds__(1024) void k_bsum(const int* __restrict__ cnt,
                                               int* __restrict__ bsum){
  int blk = blockIdx.x;
  int b = blk / CPB, ch = blk - b * CPB;
  const int* src = cnt + (long long)b * NN;
  int base = ch * SCAN_CHUNK + threadIdx.x * 4;
  int s = 0;
  #pragma unroll
  for (int k = 0; k < 4; ++k){
    int i = base + k;
    if (i < NN) s += src[i];
  }
  __shared__ int sd[1024];
  sd[threadIdx.x] = s;
  __syncthreads();
  for (int off = 512; off > 0; off >>= 1){
    if (threadIdx.x < off) sd[threadIdx.x] += sd[threadIdx.x + off];
    __syncthreads();
  }
  if (threadIdx.x == 0) bsum[blk] = sd[0];
}

__global__ __launch_bounds__(64) void k_bscan(const int* __restrict__ bsum,
                                              int* __restrict__ boff,
                                              int* __restrict__ rp){
  int b = threadIdx.x;
  if (b >= BB) return;
  int run = 0;
  for (int c = 0; c < CPB; ++c){
    boff[b * CPB + c] = run;
    run += bsum[b * CPB + c];
  }
  rp[(long long)b * (NN + 1) + NN] = run;
}

__global__ __launch_bounds__(1024) void k_scan2(const int* __restrict__ cnt,
                                                const int* __restrict__ boff,
                                                int* __restrict__ rp,
                                                int* __restrict__ tp){
  int blk = blockIdx.x;
  int b = blk / CPB, ch = blk - b * CPB;
  const int* src = cnt + (long long)b * NN;
  int* rpo = rp + (long long)b * (NN + 1);
  int* tpo = tp + (long long)b * NN;
  int base = ch * SCAN_CHUNK + threadIdx.x * 4;
  int v[4]; int tsum = 0;
  #pragma unroll
  for (int k = 0; k < 4; ++k){
    int i = base + k;
    v[k] = (i < NN) ? src[i] : 0;
    tsum += v[k];
  }
  __shared__ int sd[1024];
  sd[threadIdx.x] = tsum;
  __syncthreads();
  for (int off = 1; off < 1024; off <<= 1){
    int t = (threadIdx.x >= off) ? sd[threadIdx.x - off] : 0;
    __syncthreads();
    sd[threadIdx.x] += t;
    __syncthreads();
  }
  int excl = boff[blk] + sd[threadIdx.x] - tsum;
  #pragma unroll
  for (int k = 0; k < 4; ++k){
    int i = base + k;
    if (i < NN){ rpo[i] = excl; tpo[i] = excl; }
    excl += v[k];
  }
}

// ---------------- pass 2: ONE bucket per XCD per launch --------------------
__global__ __launch_bounds__(256) void k_p2(const int* __restrict__ gcnt,
                                            const int2* __restrict__ stg,
                                            int* __restrict__ tp,
                                            int2* __restrict__ cpk,
                                            int L){
  int x = blockIdx.x & 7;
  int j = blockIdx.x >> 3;                   // P2J chunks per bucket
  int bucket = L * 8 + x;
  int n = min(gcnt[bucket * CSTR], CAP1);
  int beh = bucket / P1B, part = bucket - beh * P1B;
  int rowbase = part * PR1;
  const int2* st = stg + (long long)bucket * CAP1;
  int* tpb = tp + (long long)beh * NN;
  int2* dst = cpk + (long long)beh * NNZE;
  int chunk = (n + P2J - 1) / P2J;
  int lo = j * chunk, hi = min(n, lo + chunk);
  for (int i = lo + threadIdx.x; i < hi; i += 256){
    int2 e = st[i];
    int row = rowbase + (int)((unsigned)e.x >> 18);
    int col = e.x & 0x3FFFF;
    int pos = atomicAdd(&tpb[row], 1);
    dst[pos] = make_int2(col, e.y);
  }
}

// ---------------- SpMM layer: bf16 gather -> bf16 h-table (NO acc) ---------
#define GB(NK)                                                              \
  {                                                                         \
    int   c[NK]; float v[NK]; float x[NK];                                  \
    _Pragma("unroll")                                                       \
    for (int k = 0; k < NK; ++k){                                           \
      int2 q = pk[e + k];                                                   \
      c[k] = __builtin_amdgcn_readfirstlane(q.x);                           \
      v[k] = __int_as_float(__builtin_amdgcn_readfirstlane(q.y));           \
    }                                                                       \
    _Pragma("unroll")                                                       \
    for (int k = 0; k < NK; ++k){                                           \
      unsigned w = xb[(long long)c[k] * 32 + (lane >> 1)];                  \
      x[k] = __uint_as_float((lane & 1) ? (w & 0xFFFF0000u) : (w << 16));   \
    }                                                                       \
    _Pragma("unroll")                                                       \
    for (int k = 0; k < NK; ++k){                                           \
      if (k & 1) sB = fmaf(v[k], x[k], sB);                                 \
      else       sA = fmaf(v[k], x[k], sA);                                 \
    }                                                                       \
    e += NK;                                                                \
  }

__global__ __launch_bounds__(256) void k_spmmL(const int* __restrict__ rp,
                                               const int2* __restrict__ cpk,
                                               const unsigned* __restrict__ xb,
                                               unsigned* __restrict__ dstb,
                                               int b){
  int row = blockIdx.x * (blockDim.x >> 6) + (threadIdx.x >> 6);  // < NN
  int lane = threadIdx.x & 63;
  row = __builtin_amdgcn_readfirstlane(row);
  const int* rpo = rp + (long long)b * (NN + 1);
  int s0 = __builtin_amdgcn_readfirstlane(rpo[row]);
  int s1 = __builtin_amdgcn_readfirstlane(rpo[row + 1]);
  const int2* pk = cpk + (long long)b * NNZE;
  float sA = 0.f, sB = 0.f;
  int e = s0;
  while (e + 16 <= s1) GB(16)
  if (e + 8 <= s1) GB(8)
  if (e + 4 <= s1) GB(4)
  if (e + 2 <= s1) GB(2)
  if (e < s1){
    int2 q = pk[e];
    int   c0 = __builtin_amdgcn_readfirstlane(q.x);
    float v0 = __int_as_float(__builtin_amdgcn_readfirstlane(q.y));
    unsigned w = xb[(long long)c0 * 32 + (lane >> 1)];
    float x0 = __uint_as_float((lane & 1) ? (w & 0xFFFF0000u) : (w << 16));
    sA = fmaf(v0, x0, sA);
  }
  float s = sA + sB;
  unsigned u = __float_as_uint(s);
  u += 0x7FFF + ((u >> 16) & 1);
  unsigned hb = u >> 16;                              // bf16 RN
  unsigned ot = (unsigned)__shfl_xor((int)hb, 1);
  if (!(lane & 1))
    dstb[(long long)row * 32 + (lane >> 1)] = hb | (ot << 16);
}

// ---------------- attention: score pass (lazy acc from bf16 tables) --------
__device__ __forceinline__ float fast_tanh(float x){
  float xc = fminf(fmaxf(x, -15.f), 15.f);
  float t = __expf(2.f * xc);
  return (t - 1.f) / (t + 1.f);
}

__device__ __forceinline__ void addbf(float4& a, float4& b, uint4 w){
  a.x += blo(w.x); a.y += bhi(w.x); a.z += blo(w.y); a.w += bhi(w.y);
  b.x += blo(w.z); b.y += bhi(w.z); b.z += blo(w.w); b.w += bhi(w.w);
}

__global__ __launch_bounds__(256) void k_score(const unsigned* __restrict__ egob,
                                               const unsigned* __restrict__ layall,
                                               const float* __restrict__ W1,
                                               const float* __restrict__ W2,
                                               float* __restrict__ scbuf){
  __shared__ float sW1[BB * 64 * 16];
  __shared__ float sW2[BB * 16];
  for (int i = threadIdx.x; i < BB * 64 * 16; i += blockDim.x) sW1[i] = W1[i];
  if (threadIdx.x < BB * 16) sW2[threadIdx.x] = W2[threadIdx.x];
  __syncthreads();
  int t = blockIdx.x * blockDim.x + threadIdx.x;
  if (t >= BB * NN) return;
  int b = t / NN;
  int n = t - b * NN;

  const uint4* e4 = (const uint4*)(egob + (long long)n * 32);
  const uint4* l0 = (const uint4*)(layall + ((long long)(b * 3 + 0) * NN + n) * 32);
  const uint4* l1 = (const uint4*)(layall + ((long long)(b * 3 + 1) * NN + n) * 32);
  const uint4* l2 = (const uint4*)(layall + ((long long)(b * 3 + 2) * NN + n) * 32);
  float4 v[16];
  #pragma unroll
  for (int q = 0; q < 8; ++q){
    uint4 w = e4[q];
    v[2*q]   = make_float4(blo(w.x), bhi(w.x), blo(w.y), bhi(w.y));
    v[2*q+1] = make_float4(blo(w.z), bhi(w.z), blo(w.w), bhi(w.w));
  }
  #pragma unroll
  for (int q = 0; q < 8; ++q){ uint4 w = l0[q]; addbf(v[2*q], v[2*q+1], w); }
  #pragma unroll
  for (int q = 0; q < 8; ++q){ uint4 w = l1[q]; addbf(v[2*q], v[2*q+1], w); }
  #pragma unroll
  for (int q = 0; q < 8; ++q){ uint4 w = l2[q]; addbf(v[2*q], v[2*q+1], w); }
  #pragma unroll
  for (int c = 0; c < 16; ++c){
    v[c].x *= 0.25f; v[c].y *= 0.25f; v[c].z *= 0.25f; v[c].w *= 0.25f;
  }

  for (int h = 0; h < BB; ++h){
    float hid[16];
    #pragma unroll
    for (int k = 0; k < 16; ++k) hid[k] = 0.f;
    #pragma unroll
    for (int c = 0; c < 16; ++c){
      const float* w = &sW1[h * 1024 + c * 64];
      #pragma unroll
      for (int k = 0; k < 16; ++k){
        hid[k] += v[c].x * w[k] + v[c].y * w[16 + k]
                + v[c].z * w[32 + k] + v[c].w * w[48 + k];
      }
    }
    float s = 0.f;
    #pragma unroll
    for (int k = 0; k < 16; ++k) s += fast_tanh(hid[k]) * sW2[h * 16 + k];
    scbuf[(long long)n * 9 + h * 3 + b] = s;
  }
}

// ---------------- attention: softmax + weighted sum (lazy acc) -------------
__global__ __launch_bounds__(256) void k_att2(const unsigned* __restrict__ egob,
                                              const unsigned* __restrict__ layall,
                                              const float* __restrict__ scbuf,
                                              float* __restrict__ out){
  int t = blockIdx.x * blockDim.x + threadIdx.x;   // NN*16 threads
  int n = t >> 4;
  int c = t & 15;
  if (n >= NN) return;
  float sc[9];
  #pragma unroll
  for (int i = 0; i < 9; ++i) sc[i] = scbuf[(long long)n * 9 + i];

  float a[BB][BB];
  #pragma unroll
  for (int h = 0; h < BB; ++h){
    float s0 = sc[h * 3], s1 = sc[h * 3 + 1], s2 = sc[h * 3 + 2];
    float m = fmaxf(fmaxf(s0, s1), s2);
    float e0 = __expf(s0 - m), e1 = __expf(s1 - m), e2 = __expf(s2 - m);
    float inv = 1.f / (e0 + e1 + e2);
    a[h][0] = e0 * inv; a[h][1] = e1 * inv; a[h][2] = e2 * inv;
  }
  long long ro = (long long)n * 32 + c * 2;
  unsigned eg0 = egob[ro], eg1 = egob[ro + 1];
  float4 x[BB];
  #pragma unroll
  for (int bb = 0; bb < BB; ++bb){
    const unsigned* p0 = layall + ((long long)(bb * 3 + 0) * NN) * 32 + ro;
    const unsigned* p1 = layall + ((long long)(bb * 3 + 1) * NN) * 32 + ro;
    const unsigned* p2 = layall + ((long long)(bb * 3 + 2) * NN) * 32 + ro;
    unsigned u00 = p0[0], u01 = p0[1];
    unsigned u10 = p1[0], u11 = p1[1];
    unsigned u20 = p2[0], u21 = p2[1];
    x[bb].x = 0.25f * (blo(eg0) + blo(u00) + blo(u10) + blo(u20));
    x[bb].y = 0.25f * (bhi(eg0) + bhi(u00) + bhi(u10) + bhi(u20));
    x[bb].z = 0.25f * (blo(eg1) + blo(u01) + blo(u11) + blo(u21));
    x[bb].w = 0.25f * (bhi(eg1) + bhi(u01) + bhi(u11) + bhi(u21));
  }
  #pragma unroll
  for (int h = 0; h < BB; ++h){
    float4 o;
    o.x = a[h][0]*x[0].x + a[h][1]*x[1].x + a[h][2]*x[2].x;
    o.y = a[h][0]*x[0].y + a[h][1]*x[1].y + a[h][2]*x[2].y;
    o.z = a[h][0]*x[0].z + a[h][1]*x[1].z + a[h][2]*x[2].z;
    o.w = a[h][0]*x[0].w + a[h][1]*x[1].w + a[h][2]*x[2].w;
    long long dst;
    if (n < UCNT) dst = ((long long)h * UCNT + n) * 64;
    else          dst = (long long)BB * UCNT * 64 + ((long long)h * ICNT + (n - UCNT)) * 64;
    ((float4*)(out + dst))[c] = o;
  }
}

// ---------------- launch ---------------------------------------------------
extern "C" void kernel_launch(void* const* d_in, const int* in_sizes, int n_in,
                              void* d_out, int out_size, void* d_ws, size_t ws_size,
                              hipStream_t stream){
  const float* ue   = (const float*)d_in[0];
  const float* ie   = (const float*)d_in[1];
  const float* W1   = (const float*)d_in[2];
  const float* W2   = (const float*)d_in[3];
  const float* vals = (const float*)d_in[4];
  const int*   rows = (const int*)d_in[5];
  const int*   cols = (const int*)d_in[6];
  float* out = (float*)d_out;

  char* ws = (char*)d_ws;
  size_t off = 0;
  auto alloc = [&](size_t bytes){ void* p = ws + off; off += (bytes + 255) & ~(size_t)255; return p; };
  int2*     cpk    = (int2*)alloc((size_t)BB * NNZE * 8);       // 57.6 MB
  int2*     stg    = (int2*)alloc((size_t)NBKT * CAP1 * 8);     // 59.9 MB
  unsigned* egob   = (unsigned*)alloc((size_t)NN * 32 * 4);     // 19.2 MB
  unsigned* layall = (unsigned*)alloc((size_t)9 * NN * 32 * 4); // 172.8 MB
  int*      rp     = (int*)alloc((size_t)BB * (NN + 1) * 4);
  int*      tp     = (int*)alloc((size_t)BB * NN * 4);
  int*      cnt    = (int*)alloc((size_t)BB * NN * 4);
  int*      bsum   = (int*)alloc((size_t)BB * CPB * 4);
  int*      boff   = (int*)alloc((size_t)BB * CPB * 4);
  int*      gcnt   = (int*)alloc((size_t)NBKT * CSTR * 4);
  float*    scbuf  = (float*)alloc((size_t)NN * 9 * 4);         // 5.4 MB
  (void)ws_size; (void)in_sizes; (void)n_in; (void)out_size;

  // CSR build + ego bf16 table
  k_zero2<<<(BB * NN + NBKT * CSTR + 255) / 256, 256, 0, stream>>>(cnt, gcnt);
  k_cvt<<<(int)(((long long)NN * 32 + 255) / 256), 256, 0, stream>>>(ue, ie, egob);
  k_p1<<<BB * P1BLK, 256, 0, stream>>>(rows, cols, vals, gcnt, stg);
  k_hist3<<<NBKT * HJ, 256, 0, stream>>>(gcnt, stg, cnt);
  k_bsum<<<BB * CPB, 1024, 0, stream>>>(cnt, bsum);
  k_bscan<<<1, 64, 0, stream>>>(bsum, boff, rp);
  k_scan2<<<BB * CPB, 1024, 0, stream>>>(cnt, boff, rp, tp);
  for (int L = 0; L < 6; ++L)
    k_p2<<<8 * P2J, 256, 0, stream>>>(gcnt, stg, tp, cpk, L);

  // propagate: layer-major (keeps the shared egob table hot for layer 1);
  // each dispatch writes its h-layer as a bf16 table; NO acc materialized.
  for (int l = 0; l < 3; ++l)
    for (int b = 0; b < BB; ++b){
      const unsigned* src = (l == 0) ? egob
                          : (layall + (size_t)(b * 3 + l - 1) * NN * 32);
      unsigned* dst = layall + (size_t)(b * 3 + l) * NN * 32;
      k_spmmL<<<NN / 4, 256, 0, stream>>>(rp, cpk, src, dst, b);
    }
  // attention: lazy-acc score pass + streaming combine pass
  k_score<<<(BB * NN + 255) / 256, 256, 0, stream>>>(egob, layall, W1, W2, scbuf);
  k_att2<<<(NN * 16) / 256, 256, 0, stream>>>(egob, layall, scbuf, out);
}

// Round 26
// 1042.463 us; speedup vs baseline: 1.1178x; 1.0106x over previous
//
#include <hip/hip_runtime.h>

#define UCNT 100000
#define ICNT 50000
#define BB   3
#define NNZE 2400000
#define NN   150000   // UCNT + ICNT

#define P1B   16                  // coarse parts per behavior
#define PR1   9375                // rows per part  (16*9375 = 150000)
#define CAP1  156000              // bucket capacity (mean 150000 + 16 sigma)
#define NBKT  (BB * P1B)          // 48 buckets
#define DEPTH 192                 // fifo depth (63 residue + ~32 mean burst) + overflow guard
#define FCH   64                  // flush chunk (64 * 8B = 512B contiguous)
#define P1BLK 375                 // blocks per behavior (375 * 6400 = 2400000)
#define P1CH  6400                // edges per block (13 rounds of 512, last=256)
#define CSTR  16                  // counter stride (one 64B line each)
#define HJ    8                   // hist blocks per bucket
#define P2J   128                 // chunks per bucket in p2
#define RB4   (NN / 4)            // row-blocks per behavior in spmm

#define SCAN_CHUNK 4096
#define CPB ((NN + SCAN_CHUNK - 1) / SCAN_CHUNK)

__device__ __forceinline__ float blo(unsigned u){ return __uint_as_float(u << 16); }
__device__ __forceinline__ float bhi(unsigned u){ return __uint_as_float(u & 0xFFFF0000u); }

// ---------------- fused zero: cnt + gcnt ------------------------------------
__global__ __launch_bounds__(256) void k_zero2(int* __restrict__ cnt,
                                               int* __restrict__ gcnt){
  long long i = (long long)blockIdx.x * blockDim.x + threadIdx.x;
  if (i < (long long)BB * NN) cnt[i] = 0;
  long long j = i - (long long)BB * NN;
  if (j >= 0 && j < NBKT * CSTR) gcnt[j] = 0;
}

// ---------------- ego -> packed bf16 table (one copy, behavior-shared) -----
__global__ __launch_bounds__(256) void k_cvt(const float* __restrict__ ue,
                                             const float* __restrict__ ie,
                                             unsigned* __restrict__ egob){
  long long w = (long long)blockIdx.x * blockDim.x + threadIdx.x; // u32 index
  if (w >= (long long)NN * 32) return;
  long long n = w >> 5;
  int pr = (int)(w & 31);
  const float* src = (n < UCNT) ? (ue + n * 64) : (ie + (n - UCNT) * 64);
  float2 v = *(const float2*)(src + pr * 2);
  unsigned a = __float_as_uint(v.x); a += 0x7FFF + ((a >> 16) & 1);
  unsigned b = __float_as_uint(v.y); b += 0x7FFF + ((b >> 16) & 1);
  egob[w] = (a >> 16) | (b & 0xFFFF0000u);
}

// ---------------- pass 1: LDS bin, 512 edges/round (13 rounds) -------------
__global__ __launch_bounds__(256) void k_p1(const int* __restrict__ rows,
                                            const int* __restrict__ cols,
                                            const float* __restrict__ vals,
                                            int* __restrict__ gcnt,
                                            int2* __restrict__ stg){
  __shared__ int2 lbuf[P1B][DEPTH];        // 24 KB
  __shared__ int  lcnt[P1B];
  int tid = threadIdx.x, lane = tid & 63, wv = tid >> 6;
  int beh = blockIdx.x / P1BLK;
  int blk = blockIdx.x - beh * P1BLK;
  long long ebase = (long long)beh * NNZE + (long long)blk * P1CH;
  if (tid < P1B) lcnt[tid] = 0;
  __syncthreads();

  for (int r = 0; r < 13; ++r){
    int off = r * 512 + tid * 2;
    if (off < P1CH){
      long long i = ebase + off;
      int2  rr = *(const int2*)(rows + i);
      int2  cc = *(const int2*)(cols + i);
      float2 vv = *(const float2*)(vals + i);
      #pragma unroll
      for (int k = 0; k < 2; ++k){
        int row = k ? rr.y : rr.x;
        int col = k ? cc.y : cc.x;
        float val = k ? vv.y : vv.x;
        int part = row / PR1;
        int2 ent = make_int2(((row - part * PR1) << 18) | col,
                             __float_as_int(val));
        int p = atomicAdd(&lcnt[part], 1);
        if (p < DEPTH){
          lbuf[part][p] = ent;
        } else {                                   // ~never: direct global
          int gb = atomicAdd(&gcnt[(beh * P1B + part) * CSTR], 1);
          if (gb < CAP1)
            stg[(long long)(beh * P1B + part) * CAP1 + gb] = ent;
        }
      }
    }
    __syncthreads();
    for (int pp = wv; pp < P1B; pp += 4){
      int n = min(lcnt[pp], DEPTH);
      int nf = n & ~(FCH - 1);
      if (nf > 0){
        int gb = 0;
        if (lane == 0) gb = atomicAdd(&gcnt[(beh * P1B + pp) * CSTR], nf);
        gb = __shfl(gb, 0);
        long long sb = (long long)(beh * P1B + pp) * CAP1;
        for (int k = lane; k < nf; k += 64)
          if (gb + k < CAP1) stg[sb + gb + k] = lbuf[pp][k];
        int res = n - nf;
        int2 t;
        if (lane < res) t = lbuf[pp][nf + lane];
        if (lane < res) lbuf[pp][lane] = t;
        if (lane == 0) lcnt[pp] = res;
      }
    }
    __syncthreads();
  }
  for (int pp = wv; pp < P1B; pp += 4){
    int n = min(lcnt[pp], DEPTH);
    if (n > 0){
      int gb = 0;
      if (lane == 0) gb = atomicAdd(&gcnt[(beh * P1B + pp) * CSTR], n);
      gb = __shfl(gb, 0);
      long long sb = (long long)(beh * P1B + pp) * CAP1;
      if (lane < n && gb + lane < CAP1) stg[sb + gb + lane] = lbuf[pp][lane];
    }
  }
}

// ---------------- hist3: LDS-private per-bucket histogram ------------------
__global__ __launch_bounds__(256) void k_hist3(const int* __restrict__ gcnt,
                                               const int2* __restrict__ stg,
                                               int* __restrict__ cnt){
  __shared__ int h[PR1];                     // 37.5 KB
  int bucket = blockIdx.x / HJ;
  int j = blockIdx.x - bucket * HJ;
  for (int i = threadIdx.x; i < PR1; i += 256) h[i] = 0;
  __syncthreads();
  int n = min(gcnt[bucket * CSTR], CAP1);
  const int2* st = stg + (long long)bucket * CAP1;
  int chunk = (n + HJ - 1) / HJ;
  int lo = j * chunk, hi = min(n, lo + chunk);
  for (int i = lo + threadIdx.x; i < hi; i += 256)
    atomicAdd(&h[(unsigned)st[i].x >> 18], 1);
  __syncthreads();
  int beh = bucket / P1B, part = bucket - beh * P1B;
  int* c = cnt + (long long)beh * NN + part * PR1;
  for (int i = threadIdx.x; i < PR1; i += 256){
    int v = h[i];
    if (v) atomicAdd(&c[i], v);
  }
}

// ---------------- scans (cnt -> rp, tp) ------------------------------------
__global__ __launch_bounds__(1024) void k_bsum(const int* __restrict__ cnt,
                                               int* __restrict__ bsum){
  int blk = blockIdx.x;
  int b = blk / CPB, ch = blk - b * CPB;
  const int* src = cnt + (long long)b * NN;
  int base = ch * SCAN_CHUNK + threadIdx.x * 4;
  int s = 0;
  #pragma unroll
  for (int k = 0; k < 4; ++k){
    int i = base + k;
    if (i < NN) s += src[i];
  }
  __shared__ int sd[1024];
  sd[threadIdx.x] = s;
  __syncthreads();
  for (int off = 512; off > 0; off >>= 1){
    if (threadIdx.x < off) sd[threadIdx.x] += sd[threadIdx.x + off];
    __syncthreads();
  }
  if (threadIdx.x == 0) bsum[blk] = sd[0];
}

__global__ __launch_bounds__(64) void k_bscan(const int* __restrict__ bsum,
                                              int* __restrict__ boff,
                                              int* __restrict__ rp){
  int b = threadIdx.x;
  if (b >= BB) return;
  int run = 0;
  for (int c = 0; c < CPB; ++c){
    boff[b * CPB + c] = run;
    run += bsum[b * CPB + c];
  }
  rp[(long long)b * (NN + 1) + NN] = run;
}

__global__ __launch_bounds__(1024) void k_scan2(const int* __restrict__ cnt,
                                                const int* __restrict__ boff,
                                                int* __restrict__ rp,
                                                int* __restrict__ tp){
  int blk = blockIdx.x;
  int b = blk / CPB, ch = blk - b * CPB;
  const int* src = cnt + (long long)b * NN;
  int* rpo = rp + (long long)b * (NN + 1);
  int* tpo = tp + (long long)b * NN;
  int base = ch * SCAN_CHUNK + threadIdx.x * 4;
  int v[4]; int tsum = 0;
  #pragma unroll
  for (int k = 0; k < 4; ++k){
    int i = base + k;
    v[k] = (i < NN) ? src[i] : 0;
    tsum += v[k];
  }
  __shared__ int sd[1024];
  sd[threadIdx.x] = tsum;
  __syncthreads();
  for (int off = 1; off < 1024; off <<= 1){
    int t = (threadIdx.x >= off) ? sd[threadIdx.x - off] : 0;
    __syncthreads();
    sd[threadIdx.x] += t;
    __syncthreads();
  }
  int excl = boff[blk] + sd[threadIdx.x] - tsum;
  #pragma unroll
  for (int k = 0; k < 4; ++k){
    int i = base + k;
    if (i < NN){ rpo[i] = excl; tpo[i] = excl; }
    excl += v[k];
  }
}

// ---------------- pass 2: ONE bucket per XCD per launch --------------------
__global__ __launch_bounds__(256) void k_p2(const int* __restrict__ gcnt,
                                            const int2* __restrict__ stg,
                                            int* __restrict__ tp,
                                            int2* __restrict__ cpk,
                                            int L){
  int x = blockIdx.x & 7;
  int j = blockIdx.x >> 3;                   // P2J chunks per bucket
  int bucket = L * 8 + x;
  int n = min(gcnt[bucket * CSTR], CAP1);
  int beh = bucket / P1B, part = bucket - beh * P1B;
  int rowbase = part * PR1;
  const int2* st = stg + (long long)bucket * CAP1;
  int* tpb = tp + (long long)beh * NN;
  int2* dst = cpk + (long long)beh * NNZE;
  int chunk = (n + P2J - 1) / P2J;
  int lo = j * chunk, hi = min(n, lo + chunk);
  for (int i = lo + threadIdx.x; i < hi; i += 256){
    int2 e = st[i];
    int row = rowbase + (int)((unsigned)e.x >> 18);
    int col = e.x & 0x3FFFF;
    int pos = atomicAdd(&tpb[row], 1);
    dst[pos] = make_int2(col, e.y);
  }
}

// ---------------- SpMM layer: ALL 3 behaviors in one dispatch --------------
#define GB(NK)                                                              \
  {                                                                         \
    int   c[NK]; float v[NK]; float x[NK];                                  \
    _Pragma("unroll")                                                       \
    for (int k = 0; k < NK; ++k){                                           \
      int2 q = pk[e + k];                                                   \
      c[k] = __builtin_amdgcn_readfirstlane(q.x);                           \
      v[k] = __int_as_float(__builtin_amdgcn_readfirstlane(q.y));           \
    }                                                                       \
    _Pragma("unroll")                                                       \
    for (int k = 0; k < NK; ++k){                                           \
      unsigned w = xb[(long long)c[k] * 32 + (lane >> 1)];                  \
      x[k] = __uint_as_float((lane & 1) ? (w & 0xFFFF0000u) : (w << 16));   \
    }                                                                       \
    _Pragma("unroll")                                                       \
    for (int k = 0; k < NK; ++k){                                           \
      if (k & 1) sB = fmaf(v[k], x[k], sB);                                 \
      else       sA = fmaf(v[k], x[k], sA);                                 \
    }                                                                       \
    e += NK;                                                                \
  }

__global__ __launch_bounds__(256) void k_spmmL(const int* __restrict__ rp,
                                               const int2* __restrict__ cpk,
                                               const unsigned* __restrict__ egob,
                                               unsigned* __restrict__ layall,
                                               int l){
  int b = blockIdx.x / RB4;                  // behavior
  int rb = blockIdx.x - b * RB4;
  int row = rb * 4 + (threadIdx.x >> 6);     // < NN
  int lane = threadIdx.x & 63;
  row = __builtin_amdgcn_readfirstlane(row);
  const unsigned* xb = (l == 0) ? egob
                     : (layall + (size_t)(b * 3 + l - 1) * NN * 32);
  unsigned* dstb = layall + (size_t)(b * 3 + l) * NN * 32;
  const int* rpo = rp + (long long)b * (NN + 1);
  int s0 = __builtin_amdgcn_readfirstlane(rpo[row]);
  int s1 = __builtin_amdgcn_readfirstlane(rpo[row + 1]);
  const int2* pk = cpk + (long long)b * NNZE;
  float sA = 0.f, sB = 0.f;
  int e = s0;
  while (e + 16 <= s1) GB(16)
  if (e + 8 <= s1) GB(8)
  if (e + 4 <= s1) GB(4)
  if (e + 2 <= s1) GB(2)
  if (e < s1){
    int2 q = pk[e];
    int   c0 = __builtin_amdgcn_readfirstlane(q.x);
    float v0 = __int_as_float(__builtin_amdgcn_readfirstlane(q.y));
    unsigned w = xb[(long long)c0 * 32 + (lane >> 1)];
    float x0 = __uint_as_float((lane & 1) ? (w & 0xFFFF0000u) : (w << 16));
    sA = fmaf(v0, x0, sA);
  }
  float s = sA + sB;
  unsigned u = __float_as_uint(s);
  u += 0x7FFF + ((u >> 16) & 1);
  unsigned hb = u >> 16;                              // bf16 RN
  unsigned ot = (unsigned)__shfl_xor((int)hb, 1);
  if (!(lane & 1))
    dstb[(long long)row * 32 + (lane >> 1)] = hb | (ot << 16);
}

// ---------------- attention: score pass (lazy acc from bf16 tables) --------
__device__ __forceinline__ float fast_tanh(float x){
  float xc = fminf(fmaxf(x, -15.f), 15.f);
  float t = __expf(2.f * xc);
  return (t - 1.f) / (t + 1.f);
}

__device__ __forceinline__ void addbf(float4& a, float4& b, uint4 w){
  a.x += blo(w.x); a.y += bhi(w.x); a.z += blo(w.y); a.w += bhi(w.y);
  b.x += blo(w.z); b.y += bhi(w.z); b.z += blo(w.w); b.w += bhi(w.w);
}

__global__ __launch_bounds__(256) void k_score(const unsigned* __restrict__ egob,
                                               const unsigned* __restrict__ layall,
                                               const float* __restrict__ W1,
                                               const float* __restrict__ W2,
                                               float* __restrict__ scbuf){
  __shared__ float sW1[BB * 64 * 16];
  __shared__ float sW2[BB * 16];
  for (int i = threadIdx.x; i < BB * 64 * 16; i += blockDim.x) sW1[i] = W1[i];
  if (threadIdx.x < BB * 16) sW2[threadIdx.x] = W2[threadIdx.x];
  __syncthreads();
  int t = blockIdx.x * blockDim.x + threadIdx.x;
  if (t >= BB * NN) return;
  int b = t / NN;
  int n = t - b * NN;

  const uint4* e4 = (const uint4*)(egob + (long long)n * 32);
  const uint4* l0 = (const uint4*)(layall + ((long long)(b * 3 + 0) * NN + n) * 32);
  const uint4* l1 = (const uint4*)(layall + ((long long)(b * 3 + 1) * NN + n) * 32);
  const uint4* l2 = (const uint4*)(layall + ((long long)(b * 3 + 2) * NN + n) * 32);
  float4 v[16];
  #pragma unroll
  for (int q = 0; q < 8; ++q){
    uint4 w = e4[q];
    v[2*q]   = make_float4(blo(w.x), bhi(w.x), blo(w.y), bhi(w.y));
    v[2*q+1] = make_float4(blo(w.z), bhi(w.z), blo(w.w), bhi(w.w));
  }
  #pragma unroll
  for (int q = 0; q < 8; ++q){ uint4 w = l0[q]; addbf(v[2*q], v[2*q+1], w); }
  #pragma unroll
  for (int q = 0; q < 8; ++q){ uint4 w = l1[q]; addbf(v[2*q], v[2*q+1], w); }
  #pragma unroll
  for (int q = 0; q < 8; ++q){ uint4 w = l2[q]; addbf(v[2*q], v[2*q+1], w); }
  #pragma unroll
  for (int c = 0; c < 16; ++c){
    v[c].x *= 0.25f; v[c].y *= 0.25f; v[c].z *= 0.25f; v[c].w *= 0.25f;
  }

  for (int h = 0; h < BB; ++h){
    float hid[16];
    #pragma unroll
    for (int k = 0; k < 16; ++k) hid[k] = 0.f;
    #pragma unroll
    for (int c = 0; c < 16; ++c){
      const float* w = &sW1[h * 1024 + c * 64];
      #pragma unroll
      for (int k = 0; k < 16; ++k){
        hid[k] += v[c].x * w[k] + v[c].y * w[16 + k]
                + v[c].z * w[32 + k] + v[c].w * w[48 + k];
      }
    }
    float s = 0.f;
    #pragma unroll
    for (int k = 0; k < 16; ++k) s += fast_tanh(hid[k]) * sW2[h * 16 + k];
    scbuf[(long long)n * 9 + h * 3 + b] = s;
  }
}

// ---------------- attention: softmax + weighted sum (lazy acc) -------------
__global__ __launch_bounds__(256) void k_att2(const unsigned* __restrict__ egob,
                                              const unsigned* __restrict__ layall,
                                              const float* __restrict__ scbuf,
                                              float* __restrict__ out){
  int t = blockIdx.x * blockDim.x + threadIdx.x;   // NN*16 threads
  int n = t >> 4;
  int c = t & 15;
  if (n >= NN) return;
  float sc[9];
  #pragma unroll
  for (int i = 0; i < 9; ++i) sc[i] = scbuf[(long long)n * 9 + i];

  float a[BB][BB];
  #pragma unroll
  for (int h = 0; h < BB; ++h){
    float s0 = sc[h * 3], s1 = sc[h * 3 + 1], s2 = sc[h * 3 + 2];
    float m = fmaxf(fmaxf(s0, s1), s2);
    float e0 = __expf(s0 - m), e1 = __expf(s1 - m), e2 = __expf(s2 - m);
    float inv = 1.f / (e0 + e1 + e2);
    a[h][0] = e0 * inv; a[h][1] = e1 * inv; a[h][2] = e2 * inv;
  }
  long long ro = (long long)n * 32 + c * 2;
  unsigned eg0 = egob[ro], eg1 = egob[ro + 1];
  float4 x[BB];
  #pragma unroll
  for (int bb = 0; bb < BB; ++bb){
    const unsigned* p0 = layall + ((long long)(bb * 3 + 0) * NN) * 32 + ro;
    const unsigned* p1 = layall + ((long long)(bb * 3 + 1) * NN) * 32 + ro;
    const unsigned* p2 = layall + ((long long)(bb * 3 + 2) * NN) * 32 + ro;
    unsigned u00 = p0[0], u01 = p0[1];
    unsigned u10 = p1[0], u11 = p1[1];
    unsigned u20 = p2[0], u21 = p2[1];
    x[bb].x = 0.25f * (blo(eg0) + blo(u00) + blo(u10) + blo(u20));
    x[bb].y = 0.25f * (bhi(eg0) + bhi(u00) + bhi(u10) + bhi(u20));
    x[bb].z = 0.25f * (blo(eg1) + blo(u01) + blo(u11) + blo(u21));
    x[bb].w = 0.25f * (bhi(eg1) + bhi(u01) + bhi(u11) + bhi(u21));
  }
  #pragma unroll
  for (int h = 0; h < BB; ++h){
    float4 o;
    o.x = a[h][0]*x[0].x + a[h][1]*x[1].x + a[h][2]*x[2].x;
    o.y = a[h][0]*x[0].y + a[h][1]*x[1].y + a[h][2]*x[2].y;
    o.z = a[h][0]*x[0].z + a[h][1]*x[1].z + a[h][2]*x[2].z;
    o.w = a[h][0]*x[0].w + a[h][1]*x[1].w + a[h][2]*x[2].w;
    long long dst;
    if (n < UCNT) dst = ((long long)h * UCNT + n) * 64;
    else          dst = (long long)BB * UCNT * 64 + ((long long)h * ICNT + (n - UCNT)) * 64;
    ((float4*)(out + dst))[c] = o;
  }
}

// ---------------- launch ---------------------------------------------------
extern "C" void kernel_launch(void* const* d_in, const int* in_sizes, int n_in,
                              void* d_out, int out_size, void* d_ws, size_t ws_size,
                              hipStream_t stream){
  const float* ue   = (const float*)d_in[0];
  const float* ie   = (const float*)d_in[1];
  const float* W1   = (const float*)d_in[2];
  const float* W2   = (const float*)d_in[3];
  const float* vals = (const float*)d_in[4];
  const int*   rows = (const int*)d_in[5];
  const int*   cols = (const int*)d_in[6];
  float* out = (float*)d_out;

  char* ws = (char*)d_ws;
  size_t off = 0;
  auto alloc = [&](size_t bytes){ void* p = ws + off; off += (bytes + 255) & ~(size_t)255; return p; };
  int2*     cpk    = (int2*)alloc((size_t)BB * NNZE * 8);       // 57.6 MB
  int2*     stg    = (int2*)alloc((size_t)NBKT * CAP1 * 8);     // 59.9 MB
  unsigned* egob   = (unsigned*)alloc((size_t)NN * 32 * 4);     // 19.2 MB
  unsigned* layall = (unsigned*)alloc((size_t)9 * NN * 32 * 4); // 172.8 MB
  int*      rp     = (int*)alloc((size_t)BB * (NN + 1) * 4);
  int*      tp     = (int*)alloc((size_t)BB * NN * 4);
  int*      cnt    = (int*)alloc((size_t)BB * NN * 4);
  int*      bsum   = (int*)alloc((size_t)BB * CPB * 4);
  int*      boff   = (int*)alloc((size_t)BB * CPB * 4);
  int*      gcnt   = (int*)alloc((size_t)NBKT * CSTR * 4);
  float*    scbuf  = (float*)alloc((size_t)NN * 9 * 4);         // 5.4 MB
  (void)ws_size; (void)in_sizes; (void)n_in; (void)out_size;

  // CSR build + ego bf16 table
  k_zero2<<<(BB * NN + NBKT * CSTR + 255) / 256, 256, 0, stream>>>(cnt, gcnt);
  k_cvt<<<(int)(((long long)NN * 32 + 255) / 256), 256, 0, stream>>>(ue, ie, egob);
  k_p1<<<BB * P1BLK, 256, 0, stream>>>(rows, cols, vals, gcnt, stg);
  k_hist3<<<NBKT * HJ, 256, 0, stream>>>(gcnt, stg, cnt);
  k_bsum<<<BB * CPB, 1024, 0, stream>>>(cnt, bsum);
  k_bscan<<<1, 64, 0, stream>>>(bsum, boff, rp);
  k_scan2<<<BB * CPB, 1024, 0, stream>>>(cnt, boff, rp, tp);
  for (int L = 0; L < 6; ++L)
    k_p2<<<8 * P2J, 256, 0, stream>>>(gcnt, stg, tp, cpk, L);

  // propagate: one dispatch per LAYER (all 3 behaviors; sources L3-fit)
  for (int l = 0; l < 3; ++l)
    k_spmmL<<<BB * RB4, 256, 0, stream>>>(rp, cpk, egob, layall, l);

  // attention: lazy-acc score pass + streaming combine pass
  k_score<<<(BB * NN + 255) / 256, 256, 0, stream>>>(egob, layall, W1, W2, scbuf);
  k_att2<<<(NN * 16) / 256, 256, 0, stream>>>(egob, layall, scbuf, out);
}